// Round 8
// baseline (296.818 us; speedup 1.0000x reference)
//
#include <hip/hip_runtime.h>
#include <cstddef>
#include <cstdint>

// Problem constants (match reference)
#define BATCH 2
#define SEQ 8192
#define CH 256
#define NLM 40
#define MROWS (BATCH * SEQ)   // 16384
#define INV_SCALE 0.0625f     // 1/sqrt(256)

typedef unsigned short ushort_t;
typedef __attribute__((ext_vector_type(8))) short short8;    // 8 bf16 (4 VGPRs)
typedef __attribute__((ext_vector_type(4))) float floatx4;   // MFMA acc

// round-to-nearest-even fp32 -> bf16
__device__ __forceinline__ ushort_t f2bf(float f) {
    unsigned int u = __float_as_uint(f);
    u += 0x7FFFu + ((u >> 16) & 1u);
    return (ushort_t)(u >> 16);
}
__device__ __forceinline__ float bf2f(ushort_t u) {
    return __uint_as_float(((unsigned)u) << 16);
}

// ---------------------------------------------------------------------------
// convert_colsum: xbf = bf16(x); xsum[b][c] = sum_n x[b][n][c].
// grid (SEQ/64, B), block 256.
// INDEX MAP (R7 crash fix): col group c4=(t&63)*4 — one wave spans one full
// 256-col row (coalesced); row group rg=t>>6 handles rows rg+4i (16 rows).
// R7's version used t*4 (0..1020) against 256-col rows -> OOB read past the
// query allocation -> HSA aperture fault -> SIGABRT. 4 atomics/col per block.
// xsum pre-zeroed.
// ---------------------------------------------------------------------------
__global__ __launch_bounds__(256) void convert_colsum(const float* __restrict__ x,
                                                      ushort_t* __restrict__ xbf,
                                                      float* __restrict__ xsum) {
    const int b = blockIdx.y;
    const int r0 = blockIdx.x * 64;
    const int t = threadIdx.x;
    const int c4 = (t & 63) * 4;     // 0..252
    const int rg = t >> 6;           // 0..3
    const float* base = x + ((size_t)b * SEQ + r0) * 256;
    ushort_t* obase = xbf + ((size_t)b * SEQ + r0) * 256;
    float4 s = {0.f, 0.f, 0.f, 0.f};
#pragma unroll 4
    for (int i = 0; i < 16; i++) {
        const int r = rg + i * 4;    // 0..63
        const float4 a = *(const float4*)&base[(size_t)r * 256 + c4];
        uint2 o;
        o.x = f2bf(a.x) | ((unsigned)f2bf(a.y) << 16);
        o.y = f2bf(a.z) | ((unsigned)f2bf(a.w) << 16);
        *(uint2*)&obase[(size_t)r * 256 + c4] = o;
        s.x += a.x; s.y += a.y; s.z += a.z; s.w += a.w;
    }
    atomicAdd(&xsum[b * 256 + c4 + 0], s.x);
    atomicAdd(&xsum[b * 256 + c4 + 1], s.y);
    atomicAdd(&xsum[b * 256 + c4 + 2], s.z);
    atomicAdd(&xsum[b * 256 + c4 + 3], s.w);
}

// ---------------------------------------------------------------------------
// convert_w: 4 weight matrices [256][256] fp32 -> bf16 (concat in wbf).
// grid (32, 4), block 256.
// ---------------------------------------------------------------------------
__global__ __launch_bounds__(256) void convert_w(const float* __restrict__ w0,
                                                 const float* __restrict__ w1,
                                                 const float* __restrict__ w2,
                                                 const float* __restrict__ w3,
                                                 ushort_t* __restrict__ wbf) {
    const float* src = (blockIdx.y == 0) ? w0 : (blockIdx.y == 1) ? w1
                     : (blockIdx.y == 2) ? w2 : w3;
    ushort_t* dst = wbf + (size_t)blockIdx.y * 65536;
    const size_t i = ((size_t)blockIdx.x * 256 + threadIdx.x) * 8;
    const float4 a = *(const float4*)&src[i];
    const float4 c = *(const float4*)&src[i + 4];
    uint4 o;
    o.x = f2bf(a.x) | ((unsigned)f2bf(a.y) << 16);
    o.y = f2bf(a.z) | ((unsigned)f2bf(a.w) << 16);
    o.z = f2bf(c.x) | ((unsigned)f2bf(c.y) << 16);
    o.w = f2bf(c.z) | ((unsigned)f2bf(c.w) << 16);
    *(uint4*)&dst[i] = o;
}

// ---------------------------------------------------------------------------
// gemm_qkv: fused q/k/v projection, bf16 in AND out. grid (4, 128, 3):
// z selects {Wq,Wk,Wv} and output slab. Tile 128x64, 4 waves,
// mfma 16x16x32 bf16, LDS row stride 40 bf16 (b128-aligned, 2-way bank
// aliasing = free per m136).
// Fragment layouts (m89/m120-verified): A[m=lane&15][k=quad*8+j];
// B lane n holds W[o0+n][k=quad*8+j]; D col=lane&15,row=quad*4+reg.
// ---------------------------------------------------------------------------
__global__ __launch_bounds__(256) void gemm_qkv(const ushort_t* __restrict__ xbf,
                                                const ushort_t* __restrict__ wbf,
                                                const float* __restrict__ bq,
                                                const float* __restrict__ bk,
                                                const float* __restrict__ bv,
                                                ushort_t* __restrict__ qkv) {
    __shared__ __align__(16) ushort_t As[128 * 40];
    __shared__ __align__(16) ushort_t Bs[64 * 40];
    const int z = blockIdx.z;
    const ushort_t* __restrict__ Wbf = wbf + (size_t)z * 65536;
    const float* __restrict__ bias = (z == 0) ? bq : (z == 1) ? bk : bv;
    ushort_t* __restrict__ out = qkv + (size_t)z * MROWS * 256;
    const int t = threadIdx.x;
    const int o0 = blockIdx.x * 64;
    const int m0 = blockIdx.y * 128;
    const int lane = t & 63;
    const int w = t >> 6;
    const int quad = lane >> 4;
    const int l16 = lane & 15;

    floatx4 acc[2][4];
#pragma unroll
    for (int rt = 0; rt < 2; rt++)
#pragma unroll
        for (int ct = 0; ct < 4; ct++) acc[rt][ct] = (floatx4){0.f, 0.f, 0.f, 0.f};

    for (int kc = 0; kc < 256; kc += 32) {
#pragma unroll
        for (int u = 0; u < 2; u++) {
            const int cid = t + u * 256;
            const int row = cid >> 2, off = cid & 3;
            *(uint4*)&As[row * 40 + off * 8] =
                *(const uint4*)&xbf[(size_t)(m0 + row) * 256 + kc + off * 8];
        }
        {
            const int row = t >> 2, off = t & 3;
            *(uint4*)&Bs[row * 40 + off * 8] =
                *(const uint4*)&Wbf[(size_t)(o0 + row) * 256 + kc + off * 8];
        }
        __syncthreads();
        short8 a[2], b[4];
#pragma unroll
        for (int rt = 0; rt < 2; rt++)
            a[rt] = *(const short8*)&As[(w * 32 + rt * 16 + l16) * 40 + quad * 8];
#pragma unroll
        for (int ct = 0; ct < 4; ct++)
            b[ct] = *(const short8*)&Bs[(ct * 16 + l16) * 40 + quad * 8];
#pragma unroll
        for (int rt = 0; rt < 2; rt++)
#pragma unroll
            for (int ct = 0; ct < 4; ct++)
                acc[rt][ct] = __builtin_amdgcn_mfma_f32_16x16x32_bf16(
                    a[rt], b[ct], acc[rt][ct], 0, 0, 0);
        __syncthreads();
    }

#pragma unroll
    for (int rt = 0; rt < 2; rt++) {
#pragma unroll
        for (int ct = 0; ct < 4; ct++) {
            const int col = o0 + ct * 16 + l16;
            const float bb = bias[col];
#pragma unroll
            for (int reg = 0; reg < 4; reg++) {
                const int row = m0 + w * 32 + rt * 16 + quad * 4 + reg;
                out[(size_t)row * 256 + col] = f2bf(acc[rt][ct][reg] + bb);
            }
        }
    }
}

// ---------------------------------------------------------------------------
// gemm_out: final projection, bf16 inputs, fp32 out with bias + residual.
// Same structure as gemm_qkv. grid (4, 128).
// ---------------------------------------------------------------------------
__global__ __launch_bounds__(256) void gemm_out(const ushort_t* __restrict__ Abf,
                                                const ushort_t* __restrict__ Wbf,
                                                const float* __restrict__ bias,
                                                const float* __restrict__ resid,
                                                float* __restrict__ out) {
    __shared__ __align__(16) ushort_t As[128 * 40];
    __shared__ __align__(16) ushort_t Bs[64 * 40];
    const int t = threadIdx.x;
    const int o0 = blockIdx.x * 64;
    const int m0 = blockIdx.y * 128;
    const int lane = t & 63;
    const int w = t >> 6;
    const int quad = lane >> 4;
    const int l16 = lane & 15;

    floatx4 acc[2][4];
#pragma unroll
    for (int rt = 0; rt < 2; rt++)
#pragma unroll
        for (int ct = 0; ct < 4; ct++) acc[rt][ct] = (floatx4){0.f, 0.f, 0.f, 0.f};

    for (int kc = 0; kc < 256; kc += 32) {
#pragma unroll
        for (int u = 0; u < 2; u++) {
            const int cid = t + u * 256;
            const int row = cid >> 2, off = cid & 3;
            *(uint4*)&As[row * 40 + off * 8] =
                *(const uint4*)&Abf[(size_t)(m0 + row) * 256 + kc + off * 8];
        }
        {
            const int row = t >> 2, off = t & 3;
            *(uint4*)&Bs[row * 40 + off * 8] =
                *(const uint4*)&Wbf[(size_t)(o0 + row) * 256 + kc + off * 8];
        }
        __syncthreads();
        short8 a[2], b[4];
#pragma unroll
        for (int rt = 0; rt < 2; rt++)
            a[rt] = *(const short8*)&As[(w * 32 + rt * 16 + l16) * 40 + quad * 8];
#pragma unroll
        for (int ct = 0; ct < 4; ct++)
            b[ct] = *(const short8*)&Bs[(ct * 16 + l16) * 40 + quad * 8];
#pragma unroll
        for (int rt = 0; rt < 2; rt++)
#pragma unroll
            for (int ct = 0; ct < 4; ct++)
                acc[rt][ct] = __builtin_amdgcn_mfma_f32_16x16x32_bf16(
                    a[rt], b[ct], acc[rt][ct], 0, 0, 0);
        __syncthreads();
    }

#pragma unroll
    for (int rt = 0; rt < 2; rt++) {
#pragma unroll
        for (int ct = 0; ct < 4; ct++) {
            const int col = o0 + ct * 16 + l16;
            const float bb = bias[col];
#pragma unroll
            for (int reg = 0; reg < 4; reg++) {
                const int row = m0 + w * 32 + rt * 16 + quad * 4 + reg;
                out[(size_t)row * 256 + col] =
                    acc[rt][ct][reg] + bb + resid[(size_t)row * 256 + col];
            }
        }
    }
}

// ---------------------------------------------------------------------------
// ws_kernel: ranking vector in fp32, independent of bf16 q/k.
//   qs = Wq @ xsum + N*bq ;  ws[b] = Wk^T @ qs
// score_m = ws·x_m/16 + const  (const dropped — ranking-invariant).
// grid (B), block 1024.
// ---------------------------------------------------------------------------
__global__ __launch_bounds__(1024) void ws_kernel(const float* __restrict__ xsum,
                                                  const float* __restrict__ Wq,
                                                  const float* __restrict__ bq,
                                                  const float* __restrict__ Wk,
                                                  float* __restrict__ ws) {
    const int b = blockIdx.x;
    __shared__ float xs[256];
    __shared__ float qs[256];
    __shared__ float ppart[4][256];
    const int t = threadIdx.x;
    if (t < 256) xs[t] = xsum[b * 256 + t];
    __syncthreads();
    const int lane = t & 63, w = t >> 6;
    for (int g = 0; g < 16; g++) {
        const int o = w * 16 + g;
        const float4 wq = *(const float4*)&Wq[(size_t)o * 256 + lane * 4];
        const float4 x4 = *(const float4*)&xs[lane * 4];
        float d = wq.x * x4.x + wq.y * x4.y + wq.z * x4.z + wq.w * x4.w;
#pragma unroll
        for (int off = 32; off >= 1; off >>= 1) d += __shfl_down(d, off);
        if (lane == 0) qs[o] = d + 8192.0f * bq[o];
    }
    __syncthreads();
    const int c = t & 255, part = t >> 8;
    float a = 0.f;
    for (int o = part * 64; o < part * 64 + 64; o++)
        a += Wk[(size_t)o * 256 + c] * qs[o];
    ppart[part][c] = a;
    __syncthreads();
    if (t < 256)
        ws[b * 256 + t] = ppart[0][t] + ppart[1][t] + ppart[2][t] + ppart[3][t];
}

// ---------------------------------------------------------------------------
// score[b][m] = dot(x[b][m], ws[b]) / 16.  fp32 path (ranking precision).
// One wave per row. grid (SEQ/4, B).
// ---------------------------------------------------------------------------
__global__ __launch_bounds__(256) void score_kernel(const float* __restrict__ x,
                                                    const float* __restrict__ ws,
                                                    float* __restrict__ score) {
    const int b = blockIdx.y;
    const int m = blockIdx.x * 4 + (threadIdx.x >> 6);
    const int lane = threadIdx.x & 63;
    const float4 kv = *(const float4*)&x[((size_t)b * SEQ + m) * 256 + lane * 4];
    const float4 qs = *(const float4*)&ws[b * 256 + lane * 4];
    float d = kv.x * qs.x + kv.y * qs.y + kv.z * qs.z + kv.w * qs.w;
#pragma unroll
    for (int off = 32; off >= 1; off >>= 1) d += __shfl_down(d, off);
    if (lane == 0) score[(size_t)b * SEQ + m] = d * INV_SCALE;
}

// ---------------------------------------------------------------------------
// Top-40 + gather via RADIX-SELECT (R6-verified). grid (B), block 1024.
// kmat bf16; sel written fp32.
// ---------------------------------------------------------------------------
__global__ __launch_bounds__(1024) void topk_gather(const float* __restrict__ score,
                                                    const ushort_t* __restrict__ kmat,
                                                    float* __restrict__ sel) {
    const int b = blockIdx.x;
    const int t = threadIdx.x;
    __shared__ unsigned hist[256];
    __shared__ unsigned wsum[64];
    __shared__ unsigned sPrefix, sMask, sRem, sNeq;
    __shared__ int sNgt;
    __shared__ int top[NLM];
    __shared__ unsigned topkey[NLM];

    unsigned key[8];
#pragma unroll
    for (int j = 0; j < 8; j++) {
        const unsigned u = __float_as_uint(score[(size_t)b * SEQ + t + j * 1024]);
        key[j] = u ^ (unsigned)(((int)u >> 31) | 0x80000000);
    }
    if (t == 0) { sPrefix = 0; sMask = 0; sRem = NLM; sNgt = 0; sNeq = 0; }

    for (int lvl = 0; lvl < 4; lvl++) {
        const int shift = 24 - 8 * lvl;
        if (t < 256) hist[t] = 0;
        __syncthreads();
        const unsigned pfx = sPrefix, msk = sMask;
#pragma unroll
        for (int j = 0; j < 8; j++)
            if (((key[j] ^ pfx) & msk) == 0)
                atomicAdd(&hist[(key[j] >> shift) & 255u], 1u);
        __syncthreads();
        if (t < 64) wsum[t] = hist[t * 4] + hist[t * 4 + 1] + hist[t * 4 + 2] + hist[t * 4 + 3];
        __syncthreads();
        if (t == 0) {
            unsigned rem = sRem, cum = 0;
            int g = 63;
            for (; g > 0; g--) { if (cum + wsum[g] >= rem) break; cum += wsum[g]; }
            int d = g * 4 + 3;
            for (; d > g * 4; d--) { if (cum + hist[d] >= rem) break; cum += hist[d]; }
            sRem = rem - cum;
            sPrefix |= ((unsigned)d) << shift;
            sMask |= 255u << shift;
        }
        __syncthreads();
    }
    const unsigned K40 = sPrefix;
    const unsigned rem = sRem;
    const int ngt = NLM - (int)rem;

#pragma unroll
    for (int j = 0; j < 8; j++) {
        if (key[j] > K40) {
            const int slot = atomicAdd(&sNgt, 1);
            top[slot] = t + j * 1024; topkey[slot] = key[j];
        } else if (key[j] == K40) {
            const unsigned e = atomicAdd(&sNeq, 1u);
            if (e < rem) {
                const int slot = ngt + (int)e;
                top[slot] = t + j * 1024; topkey[slot] = key[j];
            }
        }
    }
    __syncthreads();

    if (t < 64) {
        unsigned long long c = (t < NLM)
            ? ((((unsigned long long)(~topkey[t])) << 32) | (unsigned)top[t])
            : 0xFFFFFFFFFFFFFFFFull;
#pragma unroll
        for (int kk = 2; kk <= 64; kk <<= 1) {
#pragma unroll
            for (int j = kk >> 1; j >= 1; j >>= 1) {
                const unsigned long long o = __shfl_xor(c, j);
                const bool takeMin = ((t & kk) == 0) == ((t & j) == 0);
                const bool less = c < o;
                c = (takeMin == less) ? c : o;
            }
        }
        if (t < NLM) top[t] = (int)(c & 0xFFFFFFFFu);
    }
    __syncthreads();

    for (int f = t; f < NLM * 256; f += 1024) {
        const int j = f >> 8;
        const int cc = f & 255;
        sel[(size_t)b * NLM * 256 + f] = bf2f(kmat[((size_t)b * SEQ + top[j]) * 256 + cc]);
    }
}

// ---------------------------------------------------------------------------
// sim softmax: sim[b][n][lm] = softmax_lm(A[b][n]·sel[b][lm] / 16).
// A bf16 (converted to fp32 during LDS staging); sel fp32.
// grid (SEQ/64, B), block 256; thread: row r=t>>2, lm group c=t&3 (10 each).
// Bounded unroll (R3 spill lesson).
// ---------------------------------------------------------------------------
__global__ __launch_bounds__(256, 4) void sim_softmax_kernel(const ushort_t* __restrict__ A,
                                                             const float* __restrict__ sel,
                                                             float* __restrict__ sim) {
    __shared__ float As_[64][68];
    __shared__ float St_[40][68];
    const int b = blockIdx.y;
    const int n0 = blockIdx.x * 64;
    const int t = threadIdx.x;
    const int r = t >> 2, c = t & 3;
    const ushort_t* __restrict__ Arow = A + ((size_t)b * SEQ + n0) * 256;
    const float* __restrict__ Sb = sel + (size_t)b * NLM * 256;

    float acc[10];
#pragma unroll
    for (int j = 0; j < 10; j++) acc[j] = 0.f;

    for (int kc = 0; kc < 256; kc += 64) {
#pragma unroll
        for (int u = 0; u < 4; u++) {
            const int f = t + u * 256;
            const int row = f >> 4;
            const int c4 = (f & 15) * 4;
            const uint2 raw = *(const uint2*)&Arow[(size_t)row * 256 + kc + c4];
            float4 fa;
            fa.x = __uint_as_float((raw.x & 0xFFFFu) << 16);
            fa.y = __uint_as_float(raw.x & 0xFFFF0000u);
            fa.z = __uint_as_float((raw.y & 0xFFFFu) << 16);
            fa.w = __uint_as_float(raw.y & 0xFFFF0000u);
            *(float4*)&As_[row][c4] = fa;
        }
#pragma unroll
        for (int u = 0; u < 3; u++) {
            const int f = t + u * 256;
            if (f < 640) {
                const int row = f >> 4;
                const int c4 = (f & 15) * 4;
                *(float4*)&St_[row][c4] = *(const float4*)&Sb[(size_t)row * 256 + kc + c4];
            }
        }
        __syncthreads();
#pragma unroll 1
        for (int i = 0; i < 64; i += 4) {
            const float4 a = *(const float4*)&As_[r][i];
#pragma unroll
            for (int j = 0; j < 10; j++) {
                const float4 s = *(const float4*)&St_[c * 10 + j][i];
                acc[j] = fmaf(a.x, s.x, acc[j]);
                acc[j] = fmaf(a.y, s.y, acc[j]);
                acc[j] = fmaf(a.z, s.z, acc[j]);
                acc[j] = fmaf(a.w, s.w, acc[j]);
            }
        }
        __syncthreads();
    }

    float mx = -1e30f;
#pragma unroll
    for (int j = 0; j < 10; j++) {
        acc[j] *= INV_SCALE;
        mx = fmaxf(mx, acc[j]);
    }
    mx = fmaxf(mx, __shfl_xor(mx, 1));
    mx = fmaxf(mx, __shfl_xor(mx, 2));
    float sum = 0.f;
#pragma unroll
    for (int j = 0; j < 10; j++) {
        acc[j] = expf(acc[j] - mx);
        sum += acc[j];
    }
    sum += __shfl_xor(sum, 1);
    sum += __shfl_xor(sum, 2);
    const float inv = 1.f / sum;
#pragma unroll
    for (int j = 0; j < 10; j++) acc[j] *= inv;

    float* __restrict__ dst = &sim[((size_t)b * SEQ + n0 + r) * NLM + c * 10];
#pragma unroll
    for (int j2 = 0; j2 < 5; j2++) {
        float2 o; o.x = acc[2 * j2]; o.y = acc[2 * j2 + 1];
        *(float2*)&dst[2 * j2] = o;
    }
}

// ---------------------------------------------------------------------------
// tmat_kernel: t[b][l][cc] = sum_m simk[b][m][l] * v[b][m][cc], v bf16.
// grid (SEQ/64, B): v read from HBM exactly ONCE. Block stages 64-row v tile
// (bf16, 32 KB) + sim tile in LDS; thread t owns column t, all 40 landmarks
// (tac[40], unroll 2). tmat pre-zeroed; 128 atomicAdds per address.
// ---------------------------------------------------------------------------
__global__ __launch_bounds__(256) void tmat_kernel(const float* __restrict__ simk,
                                                   const ushort_t* __restrict__ v,
                                                   float* __restrict__ tmat) {
    __shared__ ushort_t Vs[64 * 256];   // 32 KB
    __shared__ float Ps[64][40];        // 10 KB
    const int b  = blockIdx.y;
    const int n0 = blockIdx.x * 64;
    const int t  = threadIdx.x;

    // stage v tile: 64 rows x 256 cols bf16 = 2048 16B-chunks, 8/thread
#pragma unroll
    for (int u = 0; u < 8; u++) {
        const int cid = t + u * 256;          // 0..2047
        const int row = cid >> 5, off = (cid & 31) * 8;
        *(uint4*)&Vs[row * 256 + off] =
            *(const uint4*)&v[((size_t)b * SEQ + n0 + row) * 256 + off];
    }
    // stage sim rows: 64 x 40 contiguous floats
    float* pflat = &Ps[0][0];
    for (int f = t; f < 64 * NLM; f += 256)
        pflat[f] = simk[((size_t)b * SEQ + n0) * NLM + f];
    __syncthreads();

    float tac[40];
#pragma unroll
    for (int j = 0; j < 40; j++) tac[j] = 0.f;

#pragma unroll 2
    for (int m = 0; m < 64; m++) {
        const float vv = bf2f(Vs[m * 256 + t]);   // 2-way bank alias: free
#pragma unroll
        for (int j4 = 0; j4 < 10; j4++) {
            const float4 p = *(const float4*)&Ps[m][j4 * 4];  // broadcast
            tac[j4 * 4 + 0] = fmaf(p.x, vv, tac[j4 * 4 + 0]);
            tac[j4 * 4 + 1] = fmaf(p.y, vv, tac[j4 * 4 + 1]);
            tac[j4 * 4 + 2] = fmaf(p.z, vv, tac[j4 * 4 + 2]);
            tac[j4 * 4 + 3] = fmaf(p.w, vv, tac[j4 * 4 + 3]);
        }
    }
#pragma unroll
    for (int j = 0; j < 40; j++)
        atomicAdd(&tmat[(size_t)b * NLM * 256 + j * 256 + t], tac[j]);
}

// ---------------------------------------------------------------------------
// out_pre[g][cc] = sum_l simq[g][l] * t[b][l][cc] -> bf16 (feeds final GEMM).
// grid (MROWS/64), block 256.
// ---------------------------------------------------------------------------
__global__ __launch_bounds__(256) void out_pre_kernel(const float* __restrict__ simq,
                                                      const float* __restrict__ tmat,
                                                      ushort_t* __restrict__ outp_bf) {
    __shared__ float Pm[64][40];
    const int g0 = blockIdx.x * 64;
    const int b = g0 >> 13;
    const int t = threadIdx.x;
    float* pflat = &Pm[0][0];
    for (int f = t; f < 64 * NLM; f += 256) pflat[f] = simq[(size_t)g0 * NLM + f];
    float tc[40];
#pragma unroll
    for (int l = 0; l < 40; l++) tc[l] = tmat[(size_t)b * NLM * 256 + l * 256 + t];
    __syncthreads();
#pragma unroll 2
    for (int m = 0; m < 64; m++) {
        float a = 0.f;
#pragma unroll
        for (int j4 = 0; j4 < 10; j4++) {
            const float4 p = *(const float4*)&Pm[m][j4 * 4];
            a = fmaf(p.x, tc[j4 * 4 + 0], a);
            a = fmaf(p.y, tc[j4 * 4 + 1], a);
            a = fmaf(p.z, tc[j4 * 4 + 2], a);
            a = fmaf(p.w, tc[j4 * 4 + 3], a);
        }
        outp_bf[((size_t)g0 + m) * 256 + t] = f2bf(a);
    }
}

// ---------------------------------------------------------------------------
// Workspace (~39.5 MB total — far under the ~70 MB proven-safe watermark):
//   smalls first, then bf16 slabs. outp_bf ALIASES xbf (dead after gemm_qkv).
// ---------------------------------------------------------------------------
extern "C" void kernel_launch(void* const* d_in, const int* in_sizes, int n_in,
                              void* d_out, int out_size, void* d_ws, size_t ws_size,
                              hipStream_t stream) {
    const float* query = (const float*)d_in[0];
    const float* Wq = (const float*)d_in[1];
    const float* bq = (const float*)d_in[2];
    const float* Wk = (const float*)d_in[3];
    const float* bk = (const float*)d_in[4];
    const float* Wv = (const float*)d_in[5];
    const float* bv = (const float*)d_in[6];
    const float* Wo = (const float*)d_in[7];
    const float* bo = (const float*)d_in[8];
    float* out = (float*)d_out;

    char* p = (char*)d_ws;
    float* simq  = (float*)p;            p += (size_t)MROWS * NLM * 4;      // 2.62 MB
    float* simk  = (float*)p;            p += (size_t)MROWS * NLM * 4;      // 2.62 MB
    float* sel   = (float*)p;            p += (size_t)BATCH * NLM * 256 * 4;
    float* tmat  = (float*)p;            p += (size_t)BATCH * NLM * 256 * 4;
    float* xsum  = (float*)p;            p += (size_t)BATCH * 256 * 4;
    float* ws    = (float*)p;            p += (size_t)BATCH * 256 * 4;
    float* score = (float*)p;            p += (size_t)BATCH * SEQ * 4;
    ushort_t* qkv = (ushort_t*)p;        p += (size_t)3 * MROWS * 256 * 2;  // 25.2 MB
    ushort_t* xbf = (ushort_t*)p;        p += (size_t)MROWS * 256 * 2;      // 8.39 MB
    ushort_t* wbf = (ushort_t*)p;        p += (size_t)4 * 256 * 256 * 2;    // 512 KB
    ushort_t* qbf = qkv;
    ushort_t* kbf = qkv + (size_t)MROWS * 256;
    ushort_t* vbf = qkv + (size_t)2 * MROWS * 256;
    ushort_t* outp_bf = xbf;  // alias: xbf dead after gemm_qkv

    hipMemsetAsync(xsum, 0, (size_t)BATCH * 256 * 4, stream);
    hipMemsetAsync(tmat, 0, (size_t)BATCH * NLM * 256 * 4, stream);

    const dim3 blk(256);

    convert_colsum<<<dim3(SEQ / 64, BATCH), blk, 0, stream>>>(query, xbf, xsum);
    convert_w<<<dim3(32, 4), blk, 0, stream>>>(Wq, Wk, Wv, Wo, wbf);
    ws_kernel<<<dim3(BATCH), dim3(1024), 0, stream>>>(xsum, Wq, bq, Wk, ws);
    score_kernel<<<dim3(SEQ / 4, BATCH), blk, 0, stream>>>(query, ws, score);

    gemm_qkv<<<dim3(4, MROWS / 128, 3), blk, 0, stream>>>(xbf, wbf, bq, bk, bv, qkv);

    topk_gather<<<dim3(BATCH), dim3(1024), 0, stream>>>(score, kbf, sel);

    sim_softmax_kernel<<<dim3(SEQ / 64, BATCH), blk, 0, stream>>>(qbf, sel, simq);
    sim_softmax_kernel<<<dim3(SEQ / 64, BATCH), blk, 0, stream>>>(kbf, sel, simk);
    tmat_kernel<<<dim3(SEQ / 64, BATCH), blk, 0, stream>>>(simk, vbf, tmat);

    out_pre_kernel<<<dim3(MROWS / 64), blk, 0, stream>>>(simq, tmat, outp_bf);
    gemm_out<<<dim3(4, MROWS / 128), blk, 0, stream>>>(outp_bf, wbf + 196608, bo, query, out);
}

// Round 9
// 236.941 us; speedup vs baseline: 1.2527x; 1.2527x over previous
//
#include <hip/hip_runtime.h>
#include <cstddef>
#include <cstdint>

// Problem constants (match reference)
#define BATCH 2
#define SEQ 8192
#define CH 256
#define NLM 40
#define MROWS (BATCH * SEQ)   // 16384
#define INV_SCALE 0.0625f     // 1/sqrt(256)
#define NCBLK 256             // convert_colsum blocks per batch (SEQ/32)

typedef unsigned short ushort_t;
typedef __attribute__((ext_vector_type(8))) short short8;    // 8 bf16 (4 VGPRs)
typedef __attribute__((ext_vector_type(4))) float floatx4;   // MFMA acc

// round-to-nearest-even fp32 -> bf16
__device__ __forceinline__ ushort_t f2bf(float f) {
    unsigned int u = __float_as_uint(f);
    u += 0x7FFFu + ((u >> 16) & 1u);
    return (ushort_t)(u >> 16);
}
__device__ __forceinline__ float bf2f(ushort_t u) {
    return __uint_as_float(((unsigned)u) << 16);
}

// ---------------------------------------------------------------------------
// convert_colsum: xbf = bf16(x); partial[b][blk][c] = sum of 32 rows of col c.
// grid (SEQ/32, B) = 512 blocks (2/CU), block 256.
// Thread: col group c4=(t&63)*4 (wave spans one 256-col row, coalesced);
// row group rg=t>>6 covers rows rg+4i, i<8.
// ATOMIC-HOTSPOT FIX (R8 lesson): R8 did 262144 global atomicAdds onto 512
// addresses (~2/cyc at L2 = 55 us). Now: LDS-reduce the 4 row-groups, ONE
// plain store per column per block; final reduce folded into ws_kernel.
// ---------------------------------------------------------------------------
__global__ __launch_bounds__(256) void convert_colsum(const float* __restrict__ x,
                                                      ushort_t* __restrict__ xbf,
                                                      float* __restrict__ partial) {
    __shared__ float red[4][256];
    const int b = blockIdx.y;
    const int r0 = blockIdx.x * 32;
    const int t = threadIdx.x;
    const int c4 = (t & 63) * 4;     // 0..252
    const int rg = t >> 6;           // 0..3
    const float* base = x + ((size_t)b * SEQ + r0) * 256;
    ushort_t* obase = xbf + ((size_t)b * SEQ + r0) * 256;
    float4 s = {0.f, 0.f, 0.f, 0.f};
#pragma unroll
    for (int i = 0; i < 8; i++) {
        const int r = rg + i * 4;    // 0..31
        const float4 a = *(const float4*)&base[(size_t)r * 256 + c4];
        uint2 o;
        o.x = f2bf(a.x) | ((unsigned)f2bf(a.y) << 16);
        o.y = f2bf(a.z) | ((unsigned)f2bf(a.w) << 16);
        *(uint2*)&obase[(size_t)r * 256 + c4] = o;
        s.x += a.x; s.y += a.y; s.z += a.z; s.w += a.w;
    }
    *(float4*)&red[rg][c4] = s;
    __syncthreads();
    const float tot = red[0][t] + red[1][t] + red[2][t] + red[3][t];
    partial[((size_t)b * NCBLK + blockIdx.x) * 256 + t] = tot;
}

// ---------------------------------------------------------------------------
// convert_w: 4 weight matrices [256][256] fp32 -> bf16 (concat in wbf).
// grid (32, 4), block 256.
// ---------------------------------------------------------------------------
__global__ __launch_bounds__(256) void convert_w(const float* __restrict__ w0,
                                                 const float* __restrict__ w1,
                                                 const float* __restrict__ w2,
                                                 const float* __restrict__ w3,
                                                 ushort_t* __restrict__ wbf) {
    const float* src = (blockIdx.y == 0) ? w0 : (blockIdx.y == 1) ? w1
                     : (blockIdx.y == 2) ? w2 : w3;
    ushort_t* dst = wbf + (size_t)blockIdx.y * 65536;
    const size_t i = ((size_t)blockIdx.x * 256 + threadIdx.x) * 8;
    const float4 a = *(const float4*)&src[i];
    const float4 c = *(const float4*)&src[i + 4];
    uint4 o;
    o.x = f2bf(a.x) | ((unsigned)f2bf(a.y) << 16);
    o.y = f2bf(a.z) | ((unsigned)f2bf(a.w) << 16);
    o.z = f2bf(c.x) | ((unsigned)f2bf(c.y) << 16);
    o.w = f2bf(c.z) | ((unsigned)f2bf(c.w) << 16);
    *(uint4*)&dst[i] = o;
}

// ---------------------------------------------------------------------------
// gemm_qkv: fused q/k/v projection, bf16 in AND out. grid (4, 128, 3):
// z selects {Wq,Wk,Wv} and output slab. Tile 128x64, 4 waves,
// mfma 16x16x32 bf16, LDS row stride 40 bf16 (b128-aligned, 2-way bank
// aliasing = free per m136).
// Fragment layouts (m89/m120-verified): A[m=lane&15][k=quad*8+j];
// B lane n holds W[o0+n][k=quad*8+j]; D col=lane&15,row=quad*4+reg.
// ---------------------------------------------------------------------------
__global__ __launch_bounds__(256) void gemm_qkv(const ushort_t* __restrict__ xbf,
                                                const ushort_t* __restrict__ wbf,
                                                const float* __restrict__ bq,
                                                const float* __restrict__ bk,
                                                const float* __restrict__ bv,
                                                ushort_t* __restrict__ qkv) {
    __shared__ __align__(16) ushort_t As[128 * 40];
    __shared__ __align__(16) ushort_t Bs[64 * 40];
    const int z = blockIdx.z;
    const ushort_t* __restrict__ Wbf = wbf + (size_t)z * 65536;
    const float* __restrict__ bias = (z == 0) ? bq : (z == 1) ? bk : bv;
    ushort_t* __restrict__ out = qkv + (size_t)z * MROWS * 256;
    const int t = threadIdx.x;
    const int o0 = blockIdx.x * 64;
    const int m0 = blockIdx.y * 128;
    const int lane = t & 63;
    const int w = t >> 6;
    const int quad = lane >> 4;
    const int l16 = lane & 15;

    floatx4 acc[2][4];
#pragma unroll
    for (int rt = 0; rt < 2; rt++)
#pragma unroll
        for (int ct = 0; ct < 4; ct++) acc[rt][ct] = (floatx4){0.f, 0.f, 0.f, 0.f};

    for (int kc = 0; kc < 256; kc += 32) {
#pragma unroll
        for (int u = 0; u < 2; u++) {
            const int cid = t + u * 256;
            const int row = cid >> 2, off = cid & 3;
            *(uint4*)&As[row * 40 + off * 8] =
                *(const uint4*)&xbf[(size_t)(m0 + row) * 256 + kc + off * 8];
        }
        {
            const int row = t >> 2, off = t & 3;
            *(uint4*)&Bs[row * 40 + off * 8] =
                *(const uint4*)&Wbf[(size_t)(o0 + row) * 256 + kc + off * 8];
        }
        __syncthreads();
        short8 a[2], b[4];
#pragma unroll
        for (int rt = 0; rt < 2; rt++)
            a[rt] = *(const short8*)&As[(w * 32 + rt * 16 + l16) * 40 + quad * 8];
#pragma unroll
        for (int ct = 0; ct < 4; ct++)
            b[ct] = *(const short8*)&Bs[(ct * 16 + l16) * 40 + quad * 8];
#pragma unroll
        for (int rt = 0; rt < 2; rt++)
#pragma unroll
            for (int ct = 0; ct < 4; ct++)
                acc[rt][ct] = __builtin_amdgcn_mfma_f32_16x16x32_bf16(
                    a[rt], b[ct], acc[rt][ct], 0, 0, 0);
        __syncthreads();
    }

#pragma unroll
    for (int rt = 0; rt < 2; rt++) {
#pragma unroll
        for (int ct = 0; ct < 4; ct++) {
            const int col = o0 + ct * 16 + l16;
            const float bb = bias[col];
#pragma unroll
            for (int reg = 0; reg < 4; reg++) {
                const int row = m0 + w * 32 + rt * 16 + quad * 4 + reg;
                out[(size_t)row * 256 + col] = f2bf(acc[rt][ct][reg] + bb);
            }
        }
    }
}

// ---------------------------------------------------------------------------
// gemm_out: final projection, bf16 inputs, fp32 out with bias + residual.
// Same structure as gemm_qkv. grid (4, 128).
// ---------------------------------------------------------------------------
__global__ __launch_bounds__(256) void gemm_out(const ushort_t* __restrict__ Abf,
                                                const ushort_t* __restrict__ Wbf,
                                                const float* __restrict__ bias,
                                                const float* __restrict__ resid,
                                                float* __restrict__ out) {
    __shared__ __align__(16) ushort_t As[128 * 40];
    __shared__ __align__(16) ushort_t Bs[64 * 40];
    const int t = threadIdx.x;
    const int o0 = blockIdx.x * 64;
    const int m0 = blockIdx.y * 128;
    const int lane = t & 63;
    const int w = t >> 6;
    const int quad = lane >> 4;
    const int l16 = lane & 15;

    floatx4 acc[2][4];
#pragma unroll
    for (int rt = 0; rt < 2; rt++)
#pragma unroll
        for (int ct = 0; ct < 4; ct++) acc[rt][ct] = (floatx4){0.f, 0.f, 0.f, 0.f};

    for (int kc = 0; kc < 256; kc += 32) {
#pragma unroll
        for (int u = 0; u < 2; u++) {
            const int cid = t + u * 256;
            const int row = cid >> 2, off = cid & 3;
            *(uint4*)&As[row * 40 + off * 8] =
                *(const uint4*)&Abf[(size_t)(m0 + row) * 256 + kc + off * 8];
        }
        {
            const int row = t >> 2, off = t & 3;
            *(uint4*)&Bs[row * 40 + off * 8] =
                *(const uint4*)&Wbf[(size_t)(o0 + row) * 256 + kc + off * 8];
        }
        __syncthreads();
        short8 a[2], b[4];
#pragma unroll
        for (int rt = 0; rt < 2; rt++)
            a[rt] = *(const short8*)&As[(w * 32 + rt * 16 + l16) * 40 + quad * 8];
#pragma unroll
        for (int ct = 0; ct < 4; ct++)
            b[ct] = *(const short8*)&Bs[(ct * 16 + l16) * 40 + quad * 8];
#pragma unroll
        for (int rt = 0; rt < 2; rt++)
#pragma unroll
            for (int ct = 0; ct < 4; ct++)
                acc[rt][ct] = __builtin_amdgcn_mfma_f32_16x16x32_bf16(
                    a[rt], b[ct], acc[rt][ct], 0, 0, 0);
        __syncthreads();
    }

#pragma unroll
    for (int rt = 0; rt < 2; rt++) {
#pragma unroll
        for (int ct = 0; ct < 4; ct++) {
            const int col = o0 + ct * 16 + l16;
            const float bb = bias[col];
#pragma unroll
            for (int reg = 0; reg < 4; reg++) {
                const int row = m0 + w * 32 + rt * 16 + quad * 4 + reg;
                out[(size_t)row * 256 + col] =
                    acc[rt][ct][reg] + bb + resid[(size_t)row * 256 + col];
            }
        }
    }
}

// ---------------------------------------------------------------------------
// ws_kernel: ranking vector in fp32, independent of bf16 q/k.
//   phase 0: xs[c] = sum_blk partial[b][blk][c]   (colsum final reduce)
//   phase 1: qs = Wq @ xs + N*bq
//   phase 2: ws[b] = Wk^T @ qs
// score_m = ws·x_m/16 + const  (const dropped — ranking-invariant).
// grid (B), block 1024.
// ---------------------------------------------------------------------------
__global__ __launch_bounds__(1024) void ws_kernel(const float* __restrict__ partial,
                                                  const float* __restrict__ Wq,
                                                  const float* __restrict__ bq,
                                                  const float* __restrict__ Wk,
                                                  float* __restrict__ ws) {
    const int b = blockIdx.x;
    __shared__ float xs[256];
    __shared__ float qs[256];
    __shared__ float ppart[4][256];
    const int t = threadIdx.x;
    // phase 0: quarter q sums 64 of the 256 block-partials for its column
    {
        const int c = t & 255, qd = t >> 8;
        const float* pb = partial + ((size_t)b * NCBLK + qd * 64) * 256 + c;
        float a = 0.f;
#pragma unroll 8
        for (int i = 0; i < 64; i++) a += pb[(size_t)i * 256];
        ppart[qd][c] = a;
    }
    __syncthreads();
    if (t < 256) xs[t] = ppart[0][t] + ppart[1][t] + ppart[2][t] + ppart[3][t];
    __syncthreads();
    const int lane = t & 63, w = t >> 6;
    // phase 1: wave w computes qs[o] for o = w*16 .. w*16+15
    for (int g = 0; g < 16; g++) {
        const int o = w * 16 + g;
        const float4 wq = *(const float4*)&Wq[(size_t)o * 256 + lane * 4];
        const float4 x4 = *(const float4*)&xs[lane * 4];
        float d = wq.x * x4.x + wq.y * x4.y + wq.z * x4.z + wq.w * x4.w;
#pragma unroll
        for (int off = 32; off >= 1; off >>= 1) d += __shfl_down(d, off);
        if (lane == 0) qs[o] = d + 8192.0f * bq[o];
    }
    __syncthreads();
    // phase 2: split-K over 4 groups; ws[c] = sum_o Wk[o][c] * qs[o]
    const int c = t & 255, part = t >> 8;
    float a = 0.f;
    for (int o = part * 64; o < part * 64 + 64; o++)
        a += Wk[(size_t)o * 256 + c] * qs[o];
    ppart[part][c] = a;
    __syncthreads();
    if (t < 256)
        ws[b * 256 + t] = ppart[0][t] + ppart[1][t] + ppart[2][t] + ppart[3][t];
}

// ---------------------------------------------------------------------------
// score[b][m] = dot(x[b][m], ws[b]) / 16.  fp32 path (ranking precision).
// One wave per row. grid (SEQ/4, B).
// ---------------------------------------------------------------------------
__global__ __launch_bounds__(256) void score_kernel(const float* __restrict__ x,
                                                    const float* __restrict__ ws,
                                                    float* __restrict__ score) {
    const int b = blockIdx.y;
    const int m = blockIdx.x * 4 + (threadIdx.x >> 6);
    const int lane = threadIdx.x & 63;
    const float4 kv = *(const float4*)&x[((size_t)b * SEQ + m) * 256 + lane * 4];
    const float4 qs = *(const float4*)&ws[b * 256 + lane * 4];
    float d = kv.x * qs.x + kv.y * qs.y + kv.z * qs.z + kv.w * qs.w;
#pragma unroll
    for (int off = 32; off >= 1; off >>= 1) d += __shfl_down(d, off);
    if (lane == 0) score[(size_t)b * SEQ + m] = d * INV_SCALE;
}

// ---------------------------------------------------------------------------
// Top-40 + gather via RADIX-SELECT (R6-verified). grid (B), block 1024.
// kmat bf16; sel written fp32.
// ---------------------------------------------------------------------------
__global__ __launch_bounds__(1024) void topk_gather(const float* __restrict__ score,
                                                    const ushort_t* __restrict__ kmat,
                                                    float* __restrict__ sel) {
    const int b = blockIdx.x;
    const int t = threadIdx.x;
    __shared__ unsigned hist[256];
    __shared__ unsigned wsum[64];
    __shared__ unsigned sPrefix, sMask, sRem, sNeq;
    __shared__ int sNgt;
    __shared__ int top[NLM];
    __shared__ unsigned topkey[NLM];

    unsigned key[8];
#pragma unroll
    for (int j = 0; j < 8; j++) {
        const unsigned u = __float_as_uint(score[(size_t)b * SEQ + t + j * 1024]);
        key[j] = u ^ (unsigned)(((int)u >> 31) | 0x80000000);
    }
    if (t == 0) { sPrefix = 0; sMask = 0; sRem = NLM; sNgt = 0; sNeq = 0; }

    for (int lvl = 0; lvl < 4; lvl++) {
        const int shift = 24 - 8 * lvl;
        if (t < 256) hist[t] = 0;
        __syncthreads();
        const unsigned pfx = sPrefix, msk = sMask;
#pragma unroll
        for (int j = 0; j < 8; j++)
            if (((key[j] ^ pfx) & msk) == 0)
                atomicAdd(&hist[(key[j] >> shift) & 255u], 1u);
        __syncthreads();
        if (t < 64) wsum[t] = hist[t * 4] + hist[t * 4 + 1] + hist[t * 4 + 2] + hist[t * 4 + 3];
        __syncthreads();
        if (t == 0) {
            unsigned rem = sRem, cum = 0;
            int g = 63;
            for (; g > 0; g--) { if (cum + wsum[g] >= rem) break; cum += wsum[g]; }
            int d = g * 4 + 3;
            for (; d > g * 4; d--) { if (cum + hist[d] >= rem) break; cum += hist[d]; }
            sRem = rem - cum;
            sPrefix |= ((unsigned)d) << shift;
            sMask |= 255u << shift;
        }
        __syncthreads();
    }
    const unsigned K40 = sPrefix;
    const unsigned rem = sRem;
    const int ngt = NLM - (int)rem;

#pragma unroll
    for (int j = 0; j < 8; j++) {
        if (key[j] > K40) {
            const int slot = atomicAdd(&sNgt, 1);
            top[slot] = t + j * 1024; topkey[slot] = key[j];
        } else if (key[j] == K40) {
            const unsigned e = atomicAdd(&sNeq, 1u);
            if (e < rem) {
                const int slot = ngt + (int)e;
                top[slot] = t + j * 1024; topkey[slot] = key[j];
            }
        }
    }
    __syncthreads();

    if (t < 64) {
        unsigned long long c = (t < NLM)
            ? ((((unsigned long long)(~topkey[t])) << 32) | (unsigned)top[t])
            : 0xFFFFFFFFFFFFFFFFull;
#pragma unroll
        for (int kk = 2; kk <= 64; kk <<= 1) {
#pragma unroll
            for (int j = kk >> 1; j >= 1; j >>= 1) {
                const unsigned long long o = __shfl_xor(c, j);
                const bool takeMin = ((t & kk) == 0) == ((t & j) == 0);
                const bool less = c < o;
                c = (takeMin == less) ? c : o;
            }
        }
        if (t < NLM) top[t] = (int)(c & 0xFFFFFFFFu);
    }
    __syncthreads();

    for (int f = t; f < NLM * 256; f += 1024) {
        const int j = f >> 8;
        const int cc = f & 255;
        sel[(size_t)b * NLM * 256 + f] = bf2f(kmat[((size_t)b * SEQ + top[j]) * 256 + cc]);
    }
}

// ---------------------------------------------------------------------------
// sim softmax: sim[b][n][lm] = softmax_lm(A[b][n]·sel[b][lm] / 16).
// A bf16 (converted to fp32 during LDS staging); sel fp32.
// grid (SEQ/64, B), block 256; thread: row r=t>>2, lm group c=t&3 (10 each).
// Bounded unroll (R3 spill lesson).
// ---------------------------------------------------------------------------
__global__ __launch_bounds__(256, 4) void sim_softmax_kernel(const ushort_t* __restrict__ A,
                                                             const float* __restrict__ sel,
                                                             float* __restrict__ sim) {
    __shared__ float As_[64][68];
    __shared__ float St_[40][68];
    const int b = blockIdx.y;
    const int n0 = blockIdx.x * 64;
    const int t = threadIdx.x;
    const int r = t >> 2, c = t & 3;
    const ushort_t* __restrict__ Arow = A + ((size_t)b * SEQ + n0) * 256;
    const float* __restrict__ Sb = sel + (size_t)b * NLM * 256;

    float acc[10];
#pragma unroll
    for (int j = 0; j < 10; j++) acc[j] = 0.f;

    for (int kc = 0; kc < 256; kc += 64) {
#pragma unroll
        for (int u = 0; u < 4; u++) {
            const int f = t + u * 256;
            const int row = f >> 4;
            const int c4 = (f & 15) * 4;
            const uint2 raw = *(const uint2*)&Arow[(size_t)row * 256 + kc + c4];
            float4 fa;
            fa.x = __uint_as_float((raw.x & 0xFFFFu) << 16);
            fa.y = __uint_as_float(raw.x & 0xFFFF0000u);
            fa.z = __uint_as_float((raw.y & 0xFFFFu) << 16);
            fa.w = __uint_as_float(raw.y & 0xFFFF0000u);
            *(float4*)&As_[row][c4] = fa;
        }
#pragma unroll
        for (int u = 0; u < 3; u++) {
            const int f = t + u * 256;
            if (f < 640) {
                const int row = f >> 4;
                const int c4 = (f & 15) * 4;
                *(float4*)&St_[row][c4] = *(const float4*)&Sb[(size_t)row * 256 + kc + c4];
            }
        }
        __syncthreads();
#pragma unroll 1
        for (int i = 0; i < 64; i += 4) {
            const float4 a = *(const float4*)&As_[r][i];
#pragma unroll
            for (int j = 0; j < 10; j++) {
                const float4 s = *(const float4*)&St_[c * 10 + j][i];
                acc[j] = fmaf(a.x, s.x, acc[j]);
                acc[j] = fmaf(a.y, s.y, acc[j]);
                acc[j] = fmaf(a.z, s.z, acc[j]);
                acc[j] = fmaf(a.w, s.w, acc[j]);
            }
        }
        __syncthreads();
    }

    float mx = -1e30f;
#pragma unroll
    for (int j = 0; j < 10; j++) {
        acc[j] *= INV_SCALE;
        mx = fmaxf(mx, acc[j]);
    }
    mx = fmaxf(mx, __shfl_xor(mx, 1));
    mx = fmaxf(mx, __shfl_xor(mx, 2));
    float sum = 0.f;
#pragma unroll
    for (int j = 0; j < 10; j++) {
        acc[j] = expf(acc[j] - mx);
        sum += acc[j];
    }
    sum += __shfl_xor(sum, 1);
    sum += __shfl_xor(sum, 2);
    const float inv = 1.f / sum;
#pragma unroll
    for (int j = 0; j < 10; j++) acc[j] *= inv;

    float* __restrict__ dst = &sim[((size_t)b * SEQ + n0 + r) * NLM + c * 10];
#pragma unroll
    for (int j2 = 0; j2 < 5; j2++) {
        float2 o; o.x = acc[2 * j2]; o.y = acc[2 * j2 + 1];
        *(float2*)&dst[2 * j2] = o;
    }
}

// ---------------------------------------------------------------------------
// tmat_kernel: t[b][l][cc] = sum_m simk[b][m][l] * v[b][m][cc], v bf16.
// grid (SEQ/64, B): v read from HBM exactly ONCE. Block stages 64-row v tile
// (bf16, 32 KB) + sim tile in LDS; thread t owns column t, all 40 landmarks
// (tac[40], unroll 2). tmat pre-zeroed; 128 atomicAdds per address — spread
// over 20K addresses (no hotspot; unlike R8's colsum 512-address funnel).
// ---------------------------------------------------------------------------
__global__ __launch_bounds__(256) void tmat_kernel(const float* __restrict__ simk,
                                                   const ushort_t* __restrict__ v,
                                                   float* __restrict__ tmat) {
    __shared__ ushort_t Vs[64 * 256];   // 32 KB
    __shared__ float Ps[64][40];        // 10 KB
    const int b  = blockIdx.y;
    const int n0 = blockIdx.x * 64;
    const int t  = threadIdx.x;

    // stage v tile: 64 rows x 256 cols bf16 = 2048 16B-chunks, 8/thread
#pragma unroll
    for (int u = 0; u < 8; u++) {
        const int cid = t + u * 256;          // 0..2047
        const int row = cid >> 5, off = (cid & 31) * 8;
        *(uint4*)&Vs[row * 256 + off] =
            *(const uint4*)&v[((size_t)b * SEQ + n0 + row) * 256 + off];
    }
    // stage sim rows: 64 x 40 contiguous floats
    float* pflat = &Ps[0][0];
    for (int f = t; f < 64 * NLM; f += 256)
        pflat[f] = simk[((size_t)b * SEQ + n0) * NLM + f];
    __syncthreads();

    float tac[40];
#pragma unroll
    for (int j = 0; j < 40; j++) tac[j] = 0.f;

#pragma unroll 2
    for (int m = 0; m < 64; m++) {
        const float vv = bf2f(Vs[m * 256 + t]);   // 2-way bank alias: free
#pragma unroll
        for (int j4 = 0; j4 < 10; j4++) {
            const float4 p = *(const float4*)&Ps[m][j4 * 4];  // broadcast
            tac[j4 * 4 + 0] = fmaf(p.x, vv, tac[j4 * 4 + 0]);
            tac[j4 * 4 + 1] = fmaf(p.y, vv, tac[j4 * 4 + 1]);
            tac[j4 * 4 + 2] = fmaf(p.z, vv, tac[j4 * 4 + 2]);
            tac[j4 * 4 + 3] = fmaf(p.w, vv, tac[j4 * 4 + 3]);
        }
    }
#pragma unroll
    for (int j = 0; j < 40; j++)
        atomicAdd(&tmat[(size_t)b * NLM * 256 + j * 256 + t], tac[j]);
}

// ---------------------------------------------------------------------------
// out_pre[g][cc] = sum_l simq[g][l] * t[b][l][cc] -> bf16 (feeds final GEMM).
// grid (MROWS/64), block 256.
// ---------------------------------------------------------------------------
__global__ __launch_bounds__(256) void out_pre_kernel(const float* __restrict__ simq,
                                                      const float* __restrict__ tmat,
                                                      ushort_t* __restrict__ outp_bf) {
    __shared__ float Pm[64][40];
    const int g0 = blockIdx.x * 64;
    const int b = g0 >> 13;
    const int t = threadIdx.x;
    float* pflat = &Pm[0][0];
    for (int f = t; f < 64 * NLM; f += 256) pflat[f] = simq[(size_t)g0 * NLM + f];
    float tc[40];
#pragma unroll
    for (int l = 0; l < 40; l++) tc[l] = tmat[(size_t)b * NLM * 256 + l * 256 + t];
    __syncthreads();
#pragma unroll 2
    for (int m = 0; m < 64; m++) {
        float a = 0.f;
#pragma unroll
        for (int j4 = 0; j4 < 10; j4++) {
            const float4 p = *(const float4*)&Pm[m][j4 * 4];
            a = fmaf(p.x, tc[j4 * 4 + 0], a);
            a = fmaf(p.y, tc[j4 * 4 + 1], a);
            a = fmaf(p.z, tc[j4 * 4 + 2], a);
            a = fmaf(p.w, tc[j4 * 4 + 3], a);
        }
        outp_bf[((size_t)g0 + m) * 256 + t] = f2bf(a);
    }
}

// ---------------------------------------------------------------------------
// Workspace (~40 MB total — far under the ~70 MB proven-safe watermark):
//   smalls first, then bf16 slabs. outp_bf ALIASES xbf (dead after gemm_qkv).
// ---------------------------------------------------------------------------
extern "C" void kernel_launch(void* const* d_in, const int* in_sizes, int n_in,
                              void* d_out, int out_size, void* d_ws, size_t ws_size,
                              hipStream_t stream) {
    const float* query = (const float*)d_in[0];
    const float* Wq = (const float*)d_in[1];
    const float* bq = (const float*)d_in[2];
    const float* Wk = (const float*)d_in[3];
    const float* bk = (const float*)d_in[4];
    const float* Wv = (const float*)d_in[5];
    const float* bv = (const float*)d_in[6];
    const float* Wo = (const float*)d_in[7];
    const float* bo = (const float*)d_in[8];
    float* out = (float*)d_out;

    char* p = (char*)d_ws;
    float* simq  = (float*)p;            p += (size_t)MROWS * NLM * 4;      // 2.62 MB
    float* simk  = (float*)p;            p += (size_t)MROWS * NLM * 4;      // 2.62 MB
    float* sel   = (float*)p;            p += (size_t)BATCH * NLM * 256 * 4;
    float* tmat  = (float*)p;            p += (size_t)BATCH * NLM * 256 * 4;
    float* partial = (float*)p;          p += (size_t)BATCH * NCBLK * 256 * 4; // 512 KB
    float* ws    = (float*)p;            p += (size_t)BATCH * 256 * 4;
    float* score = (float*)p;            p += (size_t)BATCH * SEQ * 4;
    ushort_t* qkv = (ushort_t*)p;        p += (size_t)3 * MROWS * 256 * 2;  // 25.2 MB
    ushort_t* xbf = (ushort_t*)p;        p += (size_t)MROWS * 256 * 2;      // 8.39 MB
    ushort_t* wbf = (ushort_t*)p;        p += (size_t)4 * 256 * 256 * 2;    // 512 KB
    ushort_t* qbf = qkv;
    ushort_t* kbf = qkv + (size_t)MROWS * 256;
    ushort_t* vbf = qkv + (size_t)2 * MROWS * 256;
    ushort_t* outp_bf = xbf;  // alias: xbf dead after gemm_qkv

    hipMemsetAsync(tmat, 0, (size_t)BATCH * NLM * 256 * 4, stream);

    const dim3 blk(256);

    convert_colsum<<<dim3(SEQ / 32, BATCH), blk, 0, stream>>>(query, xbf, partial);
    convert_w<<<dim3(32, 4), blk, 0, stream>>>(Wq, Wk, Wv, Wo, wbf);
    ws_kernel<<<dim3(BATCH), dim3(1024), 0, stream>>>(partial, Wq, bq, Wk, ws);
    score_kernel<<<dim3(SEQ / 4, BATCH), blk, 0, stream>>>(query, ws, score);

    gemm_qkv<<<dim3(4, MROWS / 128, 3), blk, 0, stream>>>(xbf, wbf, bq, bk, bv, qkv);

    topk_gather<<<dim3(BATCH), dim3(1024), 0, stream>>>(score, kbf, sel);

    sim_softmax_kernel<<<dim3(SEQ / 64, BATCH), blk, 0, stream>>>(qbf, sel, simq);
    sim_softmax_kernel<<<dim3(SEQ / 64, BATCH), blk, 0, stream>>>(kbf, sel, simk);
    tmat_kernel<<<dim3(SEQ / 64, BATCH), blk, 0, stream>>>(simk, vbf, tmat);

    out_pre_kernel<<<dim3(MROWS / 64), blk, 0, stream>>>(simq, tmat, outp_bf);
    gemm_out<<<dim3(4, MROWS / 128), blk, 0, stream>>>(outp_bf, wbf + 196608, bo, query, out);
}

// Round 10
// 213.217 us; speedup vs baseline: 1.3921x; 1.1113x over previous
//
#include <hip/hip_runtime.h>
#include <cstddef>
#include <cstdint>

// Problem constants (match reference)
#define BATCH 2
#define SEQ 8192
#define CH 256
#define NLM 40
#define MROWS (BATCH * SEQ)   // 16384
#define INV_SCALE 0.0625f     // 1/sqrt(256)
#define NCBLK 256             // convert_colsum blocks per batch (SEQ/32)

typedef unsigned short ushort_t;
typedef __attribute__((ext_vector_type(8))) short short8;    // 8 bf16 (4 VGPRs)
typedef __attribute__((ext_vector_type(4))) float floatx4;   // MFMA acc

// round-to-nearest-even fp32 -> bf16
__device__ __forceinline__ ushort_t f2bf(float f) {
    unsigned int u = __float_as_uint(f);
    u += 0x7FFFu + ((u >> 16) & 1u);
    return (ushort_t)(u >> 16);
}
__device__ __forceinline__ float bf2f(ushort_t u) {
    return __uint_as_float(((unsigned)u) << 16);
}

// ---------------------------------------------------------------------------
// convert_colsum: xbf = bf16(x); partial[b][blk][c] = sum of 32 rows of col c.
// grid (SEQ/32, B) = 512 blocks, block 256. LDS-reduce 4 row-groups, one
// plain store per column per block (R8 atomic-hotspot lesson).
// ---------------------------------------------------------------------------
__global__ __launch_bounds__(256) void convert_colsum(const float* __restrict__ x,
                                                      ushort_t* __restrict__ xbf,
                                                      float* __restrict__ partial) {
    __shared__ float red[4][256];
    const int b = blockIdx.y;
    const int r0 = blockIdx.x * 32;
    const int t = threadIdx.x;
    const int c4 = (t & 63) * 4;     // 0..252
    const int rg = t >> 6;           // 0..3
    const float* base = x + ((size_t)b * SEQ + r0) * 256;
    ushort_t* obase = xbf + ((size_t)b * SEQ + r0) * 256;
    float4 s = {0.f, 0.f, 0.f, 0.f};
#pragma unroll
    for (int i = 0; i < 8; i++) {
        const int r = rg + i * 4;    // 0..31
        const float4 a = *(const float4*)&base[(size_t)r * 256 + c4];
        uint2 o;
        o.x = f2bf(a.x) | ((unsigned)f2bf(a.y) << 16);
        o.y = f2bf(a.z) | ((unsigned)f2bf(a.w) << 16);
        *(uint2*)&obase[(size_t)r * 256 + c4] = o;
        s.x += a.x; s.y += a.y; s.z += a.z; s.w += a.w;
    }
    *(float4*)&red[rg][c4] = s;
    __syncthreads();
    const float tot = red[0][t] + red[1][t] + red[2][t] + red[3][t];
    partial[((size_t)b * NCBLK + blockIdx.x) * 256 + t] = tot;
}

// ---------------------------------------------------------------------------
// gemm_qkv: fused q/k/v projection, bf16 A, fp32 W (converted during staging
// — convert_w kernel folded in), bf16 out via LDS-transpose epilogue.
// grid (4, 128, 3): z selects {Wq,Wk,Wv}. Tile 128x64, 4 waves,
// mfma 16x16x32 bf16. Staging LDS row stride 40 bf16; epilogue reuses As with
// row stride 72 ushorts (144 B, 16B-aligned chunks, <=2-way bank alias).
// Fragment layouts (m89/m120-verified): A[m=lane&15][k=quad*8+j];
// B lane n holds W[o0+n][k=quad*8+j]; D col=lane&15,row=quad*4+reg.
// Epilogue transpose: R9's direct C-layout stores were 2 B/lane at 32 B
// granularity (~25% store efficiency); now uint4 coalesced.
// ---------------------------------------------------------------------------
__global__ __launch_bounds__(256) void gemm_qkv(const ushort_t* __restrict__ xbf,
                                                const float* __restrict__ Wq,
                                                const float* __restrict__ Wk,
                                                const float* __restrict__ Wv,
                                                const float* __restrict__ bq,
                                                const float* __restrict__ bk,
                                                const float* __restrict__ bv,
                                                ushort_t* __restrict__ qkv) {
    __shared__ __align__(16) ushort_t As[128 * 72];  // staging uses 128*40
    __shared__ __align__(16) ushort_t Bs[64 * 40];
    const int z = blockIdx.z;
    const float* __restrict__ W = (z == 0) ? Wq : (z == 1) ? Wk : Wv;
    const float* __restrict__ bias = (z == 0) ? bq : (z == 1) ? bk : bv;
    ushort_t* __restrict__ out = qkv + (size_t)z * MROWS * 256;
    const int t = threadIdx.x;
    const int o0 = blockIdx.x * 64;
    const int m0 = blockIdx.y * 128;
    const int lane = t & 63;
    const int w = t >> 6;
    const int quad = lane >> 4;
    const int l16 = lane & 15;

    floatx4 acc[2][4];
#pragma unroll
    for (int rt = 0; rt < 2; rt++)
#pragma unroll
        for (int ct = 0; ct < 4; ct++) acc[rt][ct] = (floatx4){0.f, 0.f, 0.f, 0.f};

    for (int kc = 0; kc < 256; kc += 32) {
        // Stage A tile: 128 rows x 32 k bf16
#pragma unroll
        for (int u = 0; u < 2; u++) {
            const int cid = t + u * 256;
            const int row = cid >> 2, off = cid & 3;
            *(uint4*)&As[row * 40 + off * 8] =
                *(const uint4*)&xbf[(size_t)(m0 + row) * 256 + kc + off * 8];
        }
        // Stage W tile fp32 -> bf16 (8 floats/thread, coalesced 32 B/lane)
        {
            const int row = t >> 2, off = t & 3;
            const float* wp = &W[(size_t)(o0 + row) * 256 + kc + off * 8];
            const float4 a = *(const float4*)wp;
            const float4 c = *(const float4*)(wp + 4);
            uint4 o;
            o.x = f2bf(a.x) | ((unsigned)f2bf(a.y) << 16);
            o.y = f2bf(a.z) | ((unsigned)f2bf(a.w) << 16);
            o.z = f2bf(c.x) | ((unsigned)f2bf(c.y) << 16);
            o.w = f2bf(c.z) | ((unsigned)f2bf(c.w) << 16);
            *(uint4*)&Bs[row * 40 + off * 8] = o;
        }
        __syncthreads();
        short8 a[2], b[4];
#pragma unroll
        for (int rt = 0; rt < 2; rt++)
            a[rt] = *(const short8*)&As[(w * 32 + rt * 16 + l16) * 40 + quad * 8];
#pragma unroll
        for (int ct = 0; ct < 4; ct++)
            b[ct] = *(const short8*)&Bs[(ct * 16 + l16) * 40 + quad * 8];
#pragma unroll
        for (int rt = 0; rt < 2; rt++)
#pragma unroll
            for (int ct = 0; ct < 4; ct++)
                acc[rt][ct] = __builtin_amdgcn_mfma_f32_16x16x32_bf16(
                    a[rt], b[ct], acc[rt][ct], 0, 0, 0);
        __syncthreads();
    }

    // Epilogue: bias + bf16 into As (stride 72), then coalesced uint4 stores
#pragma unroll
    for (int rt = 0; rt < 2; rt++) {
#pragma unroll
        for (int ct = 0; ct < 4; ct++) {
            const int col = ct * 16 + l16;
            const float bb = bias[o0 + col];
#pragma unroll
            for (int reg = 0; reg < 4; reg++) {
                const int row = w * 32 + rt * 16 + quad * 4 + reg;
                As[row * 72 + col] = f2bf(acc[rt][ct][reg] + bb);
            }
        }
    }
    __syncthreads();
#pragma unroll
    for (int u = 0; u < 4; u++) {
        const int cid = t + u * 256;            // 0..1023
        const int row = cid >> 3;               // 0..127
        const int off = (cid & 7) * 8;          // 0..56 (ushorts)
        *(uint4*)&out[(size_t)(m0 + row) * 256 + o0 + off] =
            *(const uint4*)&As[row * 72 + off];
    }
}

// ---------------------------------------------------------------------------
// gemm_out: final projection. A bf16, Wo fp32 (converted during staging),
// fp32 out with bias + residual via LDS-transpose epilogue (float4 coalesced
// stores + float4 resid reads). grid (4, 128). Shared memory union: staging
// As/Bs live in the low bytes of Ft; epilogue reuses all of Ft after the
// final K-loop barrier (no lifetime overlap).
// ---------------------------------------------------------------------------
__global__ __launch_bounds__(256) void gemm_out(const ushort_t* __restrict__ Abf,
                                                const float* __restrict__ Wo,
                                                const float* __restrict__ bias,
                                                const float* __restrict__ resid,
                                                float* __restrict__ out) {
    __shared__ __align__(16) char smem[128 * 68 * 4];   // 34.8 KB
    ushort_t* As = (ushort_t*)smem;                      // 10 KB  (128*40)
    ushort_t* Bs = (ushort_t*)(smem + 128 * 40 * 2);     // 5 KB   (64*40)
    float* Ft = (float*)smem;                            // 128*68 floats
    const int t = threadIdx.x;
    const int o0 = blockIdx.x * 64;
    const int m0 = blockIdx.y * 128;
    const int lane = t & 63;
    const int w = t >> 6;
    const int quad = lane >> 4;
    const int l16 = lane & 15;

    floatx4 acc[2][4];
#pragma unroll
    for (int rt = 0; rt < 2; rt++)
#pragma unroll
        for (int ct = 0; ct < 4; ct++) acc[rt][ct] = (floatx4){0.f, 0.f, 0.f, 0.f};

    for (int kc = 0; kc < 256; kc += 32) {
#pragma unroll
        for (int u = 0; u < 2; u++) {
            const int cid = t + u * 256;
            const int row = cid >> 2, off = cid & 3;
            *(uint4*)&As[row * 40 + off * 8] =
                *(const uint4*)&Abf[(size_t)(m0 + row) * 256 + kc + off * 8];
        }
        {
            const int row = t >> 2, off = t & 3;
            const float* wp = &Wo[(size_t)(o0 + row) * 256 + kc + off * 8];
            const float4 a = *(const float4*)wp;
            const float4 c = *(const float4*)(wp + 4);
            uint4 o;
            o.x = f2bf(a.x) | ((unsigned)f2bf(a.y) << 16);
            o.y = f2bf(a.z) | ((unsigned)f2bf(a.w) << 16);
            o.z = f2bf(c.x) | ((unsigned)f2bf(c.y) << 16);
            o.w = f2bf(c.z) | ((unsigned)f2bf(c.w) << 16);
            *(uint4*)&Bs[row * 40 + off * 8] = o;
        }
        __syncthreads();
        short8 a[2], b[4];
#pragma unroll
        for (int rt = 0; rt < 2; rt++)
            a[rt] = *(const short8*)&As[(w * 32 + rt * 16 + l16) * 40 + quad * 8];
#pragma unroll
        for (int ct = 0; ct < 4; ct++)
            b[ct] = *(const short8*)&Bs[(ct * 16 + l16) * 40 + quad * 8];
#pragma unroll
        for (int rt = 0; rt < 2; rt++)
#pragma unroll
            for (int ct = 0; ct < 4; ct++)
                acc[rt][ct] = __builtin_amdgcn_mfma_f32_16x16x32_bf16(
                    a[rt], b[ct], acc[rt][ct], 0, 0, 0);
        __syncthreads();
    }

    // Epilogue: bias into Ft (stride 68), then float4 stores with resid add
#pragma unroll
    for (int rt = 0; rt < 2; rt++) {
#pragma unroll
        for (int ct = 0; ct < 4; ct++) {
            const int col = ct * 16 + l16;
            const float bb = bias[o0 + col];
#pragma unroll
            for (int reg = 0; reg < 4; reg++) {
                const int row = w * 32 + rt * 16 + quad * 4 + reg;
                Ft[row * 68 + col] = acc[rt][ct][reg] + bb;
            }
        }
    }
    __syncthreads();
#pragma unroll
    for (int u = 0; u < 8; u++) {
        const int cid = t + u * 256;            // 0..2047
        const int row = cid >> 4;               // 0..127
        const int off = (cid & 15) * 4;         // 0..60 (floats)
        const float4 v = *(const float4*)&Ft[row * 68 + off];
        const float4 r4 = *(const float4*)&resid[(size_t)(m0 + row) * 256 + o0 + off];
        float4 o;
        o.x = v.x + r4.x; o.y = v.y + r4.y; o.z = v.z + r4.z; o.w = v.w + r4.w;
        *(float4*)&out[(size_t)(m0 + row) * 256 + o0 + off] = o;
    }
}

// ---------------------------------------------------------------------------
// ws_kernel: ranking vector in fp32, independent of bf16 q/k. Also zeros tmat
// (memset dispatch folded in; ws runs before tmat_kernel in stream order).
//   phase 0: xs[c] = sum_blk partial[b][blk][c]
//   phase 1: qs = Wq @ xs + N*bq ;  phase 2: ws[b] = Wk^T @ qs
// grid (B), block 1024.
// ---------------------------------------------------------------------------
__global__ __launch_bounds__(1024) void ws_kernel(const float* __restrict__ partial,
                                                  const float* __restrict__ Wq,
                                                  const float* __restrict__ bq,
                                                  const float* __restrict__ Wk,
                                                  float* __restrict__ ws,
                                                  float* __restrict__ tmat) {
    const int b = blockIdx.x;
    __shared__ float xs[256];
    __shared__ float qs[256];
    __shared__ float ppart[4][256];
    const int t = threadIdx.x;
    // zero tmat slab for this batch (tmat_kernel atomics need it)
    {
        float* tz = tmat + (size_t)b * NLM * 256;
        for (int i = t; i < NLM * 256; i += 1024) tz[i] = 0.f;
    }
    // phase 0: quarter qd sums 64 of the 256 block-partials for its column
    {
        const int c = t & 255, qd = t >> 8;
        const float* pb = partial + ((size_t)b * NCBLK + qd * 64) * 256 + c;
        float a = 0.f;
#pragma unroll 8
        for (int i = 0; i < 64; i++) a += pb[(size_t)i * 256];
        ppart[qd][c] = a;
    }
    __syncthreads();
    if (t < 256) xs[t] = ppart[0][t] + ppart[1][t] + ppart[2][t] + ppart[3][t];
    __syncthreads();
    const int lane = t & 63, w = t >> 6;
    for (int g = 0; g < 16; g++) {
        const int o = w * 16 + g;
        const float4 wq = *(const float4*)&Wq[(size_t)o * 256 + lane * 4];
        const float4 x4 = *(const float4*)&xs[lane * 4];
        float d = wq.x * x4.x + wq.y * x4.y + wq.z * x4.z + wq.w * x4.w;
#pragma unroll
        for (int off = 32; off >= 1; off >>= 1) d += __shfl_down(d, off);
        if (lane == 0) qs[o] = d + 8192.0f * bq[o];
    }
    __syncthreads();
    const int c = t & 255, part = t >> 8;
    float a = 0.f;
    for (int o = part * 64; o < part * 64 + 64; o++)
        a += Wk[(size_t)o * 256 + c] * qs[o];
    ppart[part][c] = a;
    __syncthreads();
    if (t < 256)
        ws[b * 256 + t] = ppart[0][t] + ppart[1][t] + ppart[2][t] + ppart[3][t];
}

// ---------------------------------------------------------------------------
// score[b][m] = dot(x[b][m], ws[b]) / 16.  fp32 path (ranking precision).
// One wave per row. grid (SEQ/4, B).
// ---------------------------------------------------------------------------
__global__ __launch_bounds__(256) void score_kernel(const float* __restrict__ x,
                                                    const float* __restrict__ ws,
                                                    float* __restrict__ score) {
    const int b = blockIdx.y;
    const int m = blockIdx.x * 4 + (threadIdx.x >> 6);
    const int lane = threadIdx.x & 63;
    const float4 kv = *(const float4*)&x[((size_t)b * SEQ + m) * 256 + lane * 4];
    const float4 qs = *(const float4*)&ws[b * 256 + lane * 4];
    float d = kv.x * qs.x + kv.y * qs.y + kv.z * qs.z + kv.w * qs.w;
#pragma unroll
    for (int off = 32; off >= 1; off >>= 1) d += __shfl_down(d, off);
    if (lane == 0) score[(size_t)b * SEQ + m] = d * INV_SCALE;
}

// ---------------------------------------------------------------------------
// Top-40 + gather via RADIX-SELECT (R6-verified). grid (B), block 1024.
// kmat bf16; sel written fp32.
// ---------------------------------------------------------------------------
__global__ __launch_bounds__(1024) void topk_gather(const float* __restrict__ score,
                                                    const ushort_t* __restrict__ kmat,
                                                    float* __restrict__ sel) {
    const int b = blockIdx.x;
    const int t = threadIdx.x;
    __shared__ unsigned hist[256];
    __shared__ unsigned wsum[64];
    __shared__ unsigned sPrefix, sMask, sRem, sNeq;
    __shared__ int sNgt;
    __shared__ int top[NLM];
    __shared__ unsigned topkey[NLM];

    unsigned key[8];
#pragma unroll
    for (int j = 0; j < 8; j++) {
        const unsigned u = __float_as_uint(score[(size_t)b * SEQ + t + j * 1024]);
        key[j] = u ^ (unsigned)(((int)u >> 31) | 0x80000000);
    }
    if (t == 0) { sPrefix = 0; sMask = 0; sRem = NLM; sNgt = 0; sNeq = 0; }

    for (int lvl = 0; lvl < 4; lvl++) {
        const int shift = 24 - 8 * lvl;
        if (t < 256) hist[t] = 0;
        __syncthreads();
        const unsigned pfx = sPrefix, msk = sMask;
#pragma unroll
        for (int j = 0; j < 8; j++)
            if (((key[j] ^ pfx) & msk) == 0)
                atomicAdd(&hist[(key[j] >> shift) & 255u], 1u);
        __syncthreads();
        if (t < 64) wsum[t] = hist[t * 4] + hist[t * 4 + 1] + hist[t * 4 + 2] + hist[t * 4 + 3];
        __syncthreads();
        if (t == 0) {
            unsigned rem = sRem, cum = 0;
            int g = 63;
            for (; g > 0; g--) { if (cum + wsum[g] >= rem) break; cum += wsum[g]; }
            int d = g * 4 + 3;
            for (; d > g * 4; d--) { if (cum + hist[d] >= rem) break; cum += hist[d]; }
            sRem = rem - cum;
            sPrefix |= ((unsigned)d) << shift;
            sMask |= 255u << shift;
        }
        __syncthreads();
    }
    const unsigned K40 = sPrefix;
    const unsigned rem = sRem;
    const int ngt = NLM - (int)rem;

#pragma unroll
    for (int j = 0; j < 8; j++) {
        if (key[j] > K40) {
            const int slot = atomicAdd(&sNgt, 1);
            top[slot] = t + j * 1024; topkey[slot] = key[j];
        } else if (key[j] == K40) {
            const unsigned e = atomicAdd(&sNeq, 1u);
            if (e < rem) {
                const int slot = ngt + (int)e;
                top[slot] = t + j * 1024; topkey[slot] = key[j];
            }
        }
    }
    __syncthreads();

    if (t < 64) {
        unsigned long long c = (t < NLM)
            ? ((((unsigned long long)(~topkey[t])) << 32) | (unsigned)top[t])
            : 0xFFFFFFFFFFFFFFFFull;
#pragma unroll
        for (int kk = 2; kk <= 64; kk <<= 1) {
#pragma unroll
            for (int j = kk >> 1; j >= 1; j >>= 1) {
                const unsigned long long o = __shfl_xor(c, j);
                const bool takeMin = ((t & kk) == 0) == ((t & j) == 0);
                const bool less = c < o;
                c = (takeMin == less) ? c : o;
            }
        }
        if (t < NLM) top[t] = (int)(c & 0xFFFFFFFFu);
    }
    __syncthreads();

    for (int f = t; f < NLM * 256; f += 1024) {
        const int j = f >> 8;
        const int cc = f & 255;
        sel[(size_t)b * NLM * 256 + f] = bf2f(kmat[((size_t)b * SEQ + top[j]) * 256 + cc]);
    }
}

// ---------------------------------------------------------------------------
// sim softmax: sim[b][n][lm] = softmax_lm(A[b][n]·sel[b][lm] / 16).
// ONE dispatch for both q and k: grid (SEQ/64, B, 2), z picks input/output.
// A bf16 (converted during LDS staging); sel fp32. Thread: row r=t>>2,
// lm group c=t&3 (10 each). Bounded unroll (R3 spill lesson).
// ---------------------------------------------------------------------------
__global__ __launch_bounds__(256, 4) void sim_softmax_kernel(const ushort_t* __restrict__ qbf,
                                                             const ushort_t* __restrict__ kbf,
                                                             const float* __restrict__ sel,
                                                             float* __restrict__ simq,
                                                             float* __restrict__ simk) {
    __shared__ float As_[64][68];
    __shared__ float St_[40][68];
    const int b = blockIdx.y;
    const int n0 = blockIdx.x * 64;
    const int t = threadIdx.x;
    const int r = t >> 2, c = t & 3;
    const ushort_t* __restrict__ A = (blockIdx.z == 0) ? qbf : kbf;
    float* __restrict__ sim = (blockIdx.z == 0) ? simq : simk;
    const ushort_t* __restrict__ Arow = A + ((size_t)b * SEQ + n0) * 256;
    const float* __restrict__ Sb = sel + (size_t)b * NLM * 256;

    float acc[10];
#pragma unroll
    for (int j = 0; j < 10; j++) acc[j] = 0.f;

    for (int kc = 0; kc < 256; kc += 64) {
#pragma unroll
        for (int u = 0; u < 4; u++) {
            const int f = t + u * 256;
            const int row = f >> 4;
            const int c4 = (f & 15) * 4;
            const uint2 raw = *(const uint2*)&Arow[(size_t)row * 256 + kc + c4];
            float4 fa;
            fa.x = __uint_as_float((raw.x & 0xFFFFu) << 16);
            fa.y = __uint_as_float(raw.x & 0xFFFF0000u);
            fa.z = __uint_as_float((raw.y & 0xFFFFu) << 16);
            fa.w = __uint_as_float(raw.y & 0xFFFF0000u);
            *(float4*)&As_[row][c4] = fa;
        }
#pragma unroll
        for (int u = 0; u < 3; u++) {
            const int f = t + u * 256;
            if (f < 640) {
                const int row = f >> 4;
                const int c4 = (f & 15) * 4;
                *(float4*)&St_[row][c4] = *(const float4*)&Sb[(size_t)row * 256 + kc + c4];
            }
        }
        __syncthreads();
#pragma unroll 1
        for (int i = 0; i < 64; i += 4) {
            const float4 a = *(const float4*)&As_[r][i];
#pragma unroll
            for (int j = 0; j < 10; j++) {
                const float4 s = *(const float4*)&St_[c * 10 + j][i];
                acc[j] = fmaf(a.x, s.x, acc[j]);
                acc[j] = fmaf(a.y, s.y, acc[j]);
                acc[j] = fmaf(a.z, s.z, acc[j]);
                acc[j] = fmaf(a.w, s.w, acc[j]);
            }
        }
        __syncthreads();
    }

    float mx = -1e30f;
#pragma unroll
    for (int j = 0; j < 10; j++) {
        acc[j] *= INV_SCALE;
        mx = fmaxf(mx, acc[j]);
    }
    mx = fmaxf(mx, __shfl_xor(mx, 1));
    mx = fmaxf(mx, __shfl_xor(mx, 2));
    float sum = 0.f;
#pragma unroll
    for (int j = 0; j < 10; j++) {
        acc[j] = expf(acc[j] - mx);
        sum += acc[j];
    }
    sum += __shfl_xor(sum, 1);
    sum += __shfl_xor(sum, 2);
    const float inv = 1.f / sum;
#pragma unroll
    for (int j = 0; j < 10; j++) acc[j] *= inv;

    float* __restrict__ dst = &sim[((size_t)b * SEQ + n0 + r) * NLM + c * 10];
#pragma unroll
    for (int j2 = 0; j2 < 5; j2++) {
        float2 o; o.x = acc[2 * j2]; o.y = acc[2 * j2 + 1];
        *(float2*)&dst[2 * j2] = o;
    }
}

// ---------------------------------------------------------------------------
// tmat_kernel: t[b][l][cc] = sum_m simk[b][m][l] * v[b][m][cc], v bf16.
// grid (SEQ/64, B). tmat pre-zeroed by ws_kernel; 128 atomicAdds per address
// spread over 20K addresses (no hotspot).
// ---------------------------------------------------------------------------
__global__ __launch_bounds__(256) void tmat_kernel(const float* __restrict__ simk,
                                                   const ushort_t* __restrict__ v,
                                                   float* __restrict__ tmat) {
    __shared__ ushort_t Vs[64 * 256];   // 32 KB
    __shared__ float Ps[64][40];        // 10 KB
    const int b  = blockIdx.y;
    const int n0 = blockIdx.x * 64;
    const int t  = threadIdx.x;

#pragma unroll
    for (int u = 0; u < 8; u++) {
        const int cid = t + u * 256;          // 0..2047
        const int row = cid >> 5, off = (cid & 31) * 8;
        *(uint4*)&Vs[row * 256 + off] =
            *(const uint4*)&v[((size_t)b * SEQ + n0 + row) * 256 + off];
    }
    float* pflat = &Ps[0][0];
    for (int f = t; f < 64 * NLM; f += 256)
        pflat[f] = simk[((size_t)b * SEQ + n0) * NLM + f];
    __syncthreads();

    float tac[40];
#pragma unroll
    for (int j = 0; j < 40; j++) tac[j] = 0.f;

#pragma unroll 2
    for (int m = 0; m < 64; m++) {
        const float vv = bf2f(Vs[m * 256 + t]);   // 2-way bank alias: free
#pragma unroll
        for (int j4 = 0; j4 < 10; j4++) {
            const float4 p = *(const float4*)&Ps[m][j4 * 4];  // broadcast
            tac[j4 * 4 + 0] = fmaf(p.x, vv, tac[j4 * 4 + 0]);
            tac[j4 * 4 + 1] = fmaf(p.y, vv, tac[j4 * 4 + 1]);
            tac[j4 * 4 + 2] = fmaf(p.z, vv, tac[j4 * 4 + 2]);
            tac[j4 * 4 + 3] = fmaf(p.w, vv, tac[j4 * 4 + 3]);
        }
    }
#pragma unroll
    for (int j = 0; j < 40; j++)
        atomicAdd(&tmat[(size_t)b * NLM * 256 + j * 256 + t], tac[j]);
}

// ---------------------------------------------------------------------------
// out_pre[g][cc] = sum_l simq[g][l] * t[b][l][cc] -> bf16 (feeds final GEMM).
// grid (MROWS/64), block 256.
// ---------------------------------------------------------------------------
__global__ __launch_bounds__(256) void out_pre_kernel(const float* __restrict__ simq,
                                                      const float* __restrict__ tmat,
                                                      ushort_t* __restrict__ outp_bf) {
    __shared__ float Pm[64][40];
    const int g0 = blockIdx.x * 64;
    const int b = g0 >> 13;
    const int t = threadIdx.x;
    float* pflat = &Pm[0][0];
    for (int f = t; f < 64 * NLM; f += 256) pflat[f] = simq[(size_t)g0 * NLM + f];
    float tc[40];
#pragma unroll
    for (int l = 0; l < 40; l++) tc[l] = tmat[(size_t)b * NLM * 256 + l * 256 + t];
    __syncthreads();
#pragma unroll 2
    for (int m = 0; m < 64; m++) {
        float a = 0.f;
#pragma unroll
        for (int j4 = 0; j4 < 10; j4++) {
            const float4 p = *(const float4*)&Pm[m][j4 * 4];
            a = fmaf(p.x, tc[j4 * 4 + 0], a);
            a = fmaf(p.y, tc[j4 * 4 + 1], a);
            a = fmaf(p.z, tc[j4 * 4 + 2], a);
            a = fmaf(p.w, tc[j4 * 4 + 3], a);
        }
        outp_bf[((size_t)g0 + m) * 256 + t] = f2bf(a);
    }
}

// ---------------------------------------------------------------------------
// Workspace (~39.5 MB — far under the ~70 MB proven-safe watermark).
// 9 dispatches (was 12): convert_w folded into gemms, memset into ws_kernel,
// sim q/k into one dispatch. outp_bf ALIASES xbf (dead after gemm_qkv).
// ---------------------------------------------------------------------------
extern "C" void kernel_launch(void* const* d_in, const int* in_sizes, int n_in,
                              void* d_out, int out_size, void* d_ws, size_t ws_size,
                              hipStream_t stream) {
    const float* query = (const float*)d_in[0];
    const float* Wq = (const float*)d_in[1];
    const float* bq = (const float*)d_in[2];
    const float* Wk = (const float*)d_in[3];
    const float* bk = (const float*)d_in[4];
    const float* Wv = (const float*)d_in[5];
    const float* bv = (const float*)d_in[6];
    const float* Wo = (const float*)d_in[7];
    const float* bo = (const float*)d_in[8];
    float* out = (float*)d_out;

    char* p = (char*)d_ws;
    float* simq  = (float*)p;            p += (size_t)MROWS * NLM * 4;      // 2.62 MB
    float* simk  = (float*)p;            p += (size_t)MROWS * NLM * 4;      // 2.62 MB
    float* sel   = (float*)p;            p += (size_t)BATCH * NLM * 256 * 4;
    float* tmat  = (float*)p;            p += (size_t)BATCH * NLM * 256 * 4;
    float* partial = (float*)p;          p += (size_t)BATCH * NCBLK * 256 * 4; // 512 KB
    float* ws    = (float*)p;            p += (size_t)BATCH * 256 * 4;
    float* score = (float*)p;            p += (size_t)BATCH * SEQ * 4;
    ushort_t* qkv = (ushort_t*)p;        p += (size_t)3 * MROWS * 256 * 2;  // 25.2 MB
    ushort_t* xbf = (ushort_t*)p;        p += (size_t)MROWS * 256 * 2;      // 8.39 MB
    ushort_t* qbf = qkv;
    ushort_t* kbf = qkv + (size_t)MROWS * 256;
    ushort_t* vbf = qkv + (size_t)2 * MROWS * 256;
    ushort_t* outp_bf = xbf;  // alias: xbf dead after gemm_qkv

    const dim3 blk(256);

    convert_colsum<<<dim3(SEQ / 32, BATCH), blk, 0, stream>>>(query, xbf, partial);
    ws_kernel<<<dim3(BATCH), dim3(1024), 0, stream>>>(partial, Wq, bq, Wk, ws, tmat);
    score_kernel<<<dim3(SEQ / 4, BATCH), blk, 0, stream>>>(query, ws, score);

    gemm_qkv<<<dim3(4, MROWS / 128, 3), blk, 0, stream>>>(xbf, Wq, Wk, Wv, bq, bk, bv, qkv);

    topk_gather<<<dim3(BATCH), dim3(1024), 0, stream>>>(score, kbf, sel);

    sim_softmax_kernel<<<dim3(SEQ / 64, BATCH, 2), blk, 0, stream>>>(qbf, kbf, sel, simq, simk);
    tmat_kernel<<<dim3(SEQ / 64, BATCH), blk, 0, stream>>>(simk, vbf, tmat);

    out_pre_kernel<<<dim3(MROWS / 64), blk, 0, stream>>>(simq, tmat, outp_bf);
    gemm_out<<<dim3(4, MROWS / 128), blk, 0, stream>>>(outp_bf, Wo, bo, query, out);
}

// Round 11
// 204.660 us; speedup vs baseline: 1.4503x; 1.0418x over previous
//
#include <hip/hip_runtime.h>
#include <cstddef>
#include <cstdint>

// Problem constants (match reference)
#define BATCH 2
#define SEQ 8192
#define CH 256
#define NLM 40
#define MROWS (BATCH * SEQ)   // 16384
#define INV_SCALE 0.0625f     // 1/sqrt(256)
#define NCBLK 256             // convert_colsum blocks per batch (SEQ/32)

typedef unsigned short ushort_t;
typedef __attribute__((ext_vector_type(8))) short short8;    // 8 bf16 (4 VGPRs)
typedef __attribute__((ext_vector_type(4))) float floatx4;   // MFMA acc

// round-to-nearest-even fp32 -> bf16
__device__ __forceinline__ ushort_t f2bf(float f) {
    unsigned int u = __float_as_uint(f);
    u += 0x7FFFu + ((u >> 16) & 1u);
    return (ushort_t)(u >> 16);
}
__device__ __forceinline__ float bf2f(ushort_t u) {
    return __uint_as_float(((unsigned)u) << 16);
}

// ---------------------------------------------------------------------------
// convert_colsum: xbf = bf16(x); partial[b][blk][c] = sum of 32 rows of col c.
// grid (SEQ/32, B) = 512 blocks, block 256. LDS-reduce 4 row-groups, one
// plain store per column per block (R8 atomic-hotspot lesson).
// ---------------------------------------------------------------------------
__global__ __launch_bounds__(256) void convert_colsum(const float* __restrict__ x,
                                                      ushort_t* __restrict__ xbf,
                                                      float* __restrict__ partial) {
    __shared__ float red[4][256];
    const int b = blockIdx.y;
    const int r0 = blockIdx.x * 32;
    const int t = threadIdx.x;
    const int c4 = (t & 63) * 4;     // 0..252
    const int rg = t >> 6;           // 0..3
    const float* base = x + ((size_t)b * SEQ + r0) * 256;
    ushort_t* obase = xbf + ((size_t)b * SEQ + r0) * 256;
    float4 s = {0.f, 0.f, 0.f, 0.f};
#pragma unroll
    for (int i = 0; i < 8; i++) {
        const int r = rg + i * 4;    // 0..31
        const float4 a = *(const float4*)&base[(size_t)r * 256 + c4];
        uint2 o;
        o.x = f2bf(a.x) | ((unsigned)f2bf(a.y) << 16);
        o.y = f2bf(a.z) | ((unsigned)f2bf(a.w) << 16);
        *(uint2*)&obase[(size_t)r * 256 + c4] = o;
        s.x += a.x; s.y += a.y; s.z += a.z; s.w += a.w;
    }
    *(float4*)&red[rg][c4] = s;
    __syncthreads();
    const float tot = red[0][t] + red[1][t] + red[2][t] + red[3][t];
    partial[((size_t)b * NCBLK + blockIdx.x) * 256 + t] = tot;
}

// ---------------------------------------------------------------------------
// ws_kernel: ranking vector in fp32. Also zeros tmat (memset folded in).
//   phase 0: xs[c] = sum_blk partial[b][blk][c]
//   phase 1: qs = Wq @ xs + N*bq ;  phase 2: ws[b] = Wk^T @ qs
// grid (B), block 1024.
// ---------------------------------------------------------------------------
__global__ __launch_bounds__(1024) void ws_kernel(const float* __restrict__ partial,
                                                  const float* __restrict__ Wq,
                                                  const float* __restrict__ bq,
                                                  const float* __restrict__ Wk,
                                                  float* __restrict__ ws,
                                                  float* __restrict__ tmat) {
    const int b = blockIdx.x;
    __shared__ float xs[256];
    __shared__ float qs[256];
    __shared__ float ppart[4][256];
    const int t = threadIdx.x;
    {
        float* tz = tmat + (size_t)b * NLM * 256;
        for (int i = t; i < NLM * 256; i += 1024) tz[i] = 0.f;
    }
    {
        const int c = t & 255, qd = t >> 8;
        const float* pb = partial + ((size_t)b * NCBLK + qd * 64) * 256 + c;
        float a = 0.f;
#pragma unroll 8
        for (int i = 0; i < 64; i++) a += pb[(size_t)i * 256];
        ppart[qd][c] = a;
    }
    __syncthreads();
    if (t < 256) xs[t] = ppart[0][t] + ppart[1][t] + ppart[2][t] + ppart[3][t];
    __syncthreads();
    const int lane = t & 63, w = t >> 6;
    for (int g = 0; g < 16; g++) {
        const int o = w * 16 + g;
        const float4 wq = *(const float4*)&Wq[(size_t)o * 256 + lane * 4];
        const float4 x4 = *(const float4*)&xs[lane * 4];
        float d = wq.x * x4.x + wq.y * x4.y + wq.z * x4.z + wq.w * x4.w;
#pragma unroll
        for (int off = 32; off >= 1; off >>= 1) d += __shfl_down(d, off);
        if (lane == 0) qs[o] = d + 8192.0f * bq[o];
    }
    __syncthreads();
    const int c = t & 255, part = t >> 8;
    float a = 0.f;
    for (int o = part * 64; o < part * 64 + 64; o++)
        a += Wk[(size_t)o * 256 + c] * qs[o];
    ppart[part][c] = a;
    __syncthreads();
    if (t < 256)
        ws[b * 256 + t] = ppart[0][t] + ppart[1][t] + ppart[2][t] + ppart[3][t];
}

// ---------------------------------------------------------------------------
// gemm_qkv_score: grid (4, 128, 4).
//   z<3: q/k/v projection — bf16 A, fp32 W converted during staging, bf16 out
//        via LDS-transpose epilogue (R10-verified structure).
//   z=3: score slice — score[b][m] = dot(query[m], ws[b])/16, fp32 path
//        (ranking precision), 512 blocks x 32 rows, bit-identical to R10's
//        standalone score_kernel. Fused here to cut one dispatch (~12 us
//        launch+drain): both are ready after ws_kernel.
// ---------------------------------------------------------------------------
__global__ __launch_bounds__(256) void gemm_qkv_score(const ushort_t* __restrict__ xbf,
                                                      const float* __restrict__ Wq,
                                                      const float* __restrict__ Wk,
                                                      const float* __restrict__ Wv,
                                                      const float* __restrict__ bq,
                                                      const float* __restrict__ bk,
                                                      const float* __restrict__ bv,
                                                      ushort_t* __restrict__ qkv,
                                                      const float* __restrict__ query,
                                                      const float* __restrict__ ws,
                                                      float* __restrict__ score) {
    __shared__ __align__(16) ushort_t As[128 * 72];  // staging uses 128*40
    __shared__ __align__(16) ushort_t Bs[64 * 40];
    const int z = blockIdx.z;
    const int t = threadIdx.x;
    const int lane = t & 63;
    const int w = t >> 6;

    if (z == 3) {  // score slice
        const int blk = blockIdx.y * 4 + blockIdx.x;      // 0..511
#pragma unroll
        for (int i = 0; i < 8; i++) {
            const int g = blk * 32 + i * 4 + w;           // row 0..16383
            const int b = g >> 13;
            const int m = g & 8191;
            const float4 kv = *(const float4*)&query[(size_t)g * 256 + lane * 4];
            const float4 qs = *(const float4*)&ws[b * 256 + lane * 4];
            float d = kv.x * qs.x + kv.y * qs.y + kv.z * qs.z + kv.w * qs.w;
#pragma unroll
            for (int off = 32; off >= 1; off >>= 1) d += __shfl_down(d, off);
            if (lane == 0) score[(size_t)b * SEQ + m] = d * INV_SCALE;
        }
        return;
    }

    const float* __restrict__ W = (z == 0) ? Wq : (z == 1) ? Wk : Wv;
    const float* __restrict__ bias = (z == 0) ? bq : (z == 1) ? bk : bv;
    ushort_t* __restrict__ out = qkv + (size_t)z * MROWS * 256;
    const int o0 = blockIdx.x * 64;
    const int m0 = blockIdx.y * 128;
    const int quad = lane >> 4;
    const int l16 = lane & 15;

    floatx4 acc[2][4];
#pragma unroll
    for (int rt = 0; rt < 2; rt++)
#pragma unroll
        for (int ct = 0; ct < 4; ct++) acc[rt][ct] = (floatx4){0.f, 0.f, 0.f, 0.f};

    for (int kc = 0; kc < 256; kc += 32) {
#pragma unroll
        for (int u = 0; u < 2; u++) {
            const int cid = t + u * 256;
            const int row = cid >> 2, off = cid & 3;
            *(uint4*)&As[row * 40 + off * 8] =
                *(const uint4*)&xbf[(size_t)(m0 + row) * 256 + kc + off * 8];
        }
        {
            const int row = t >> 2, off = t & 3;
            const float* wp = &W[(size_t)(o0 + row) * 256 + kc + off * 8];
            const float4 a = *(const float4*)wp;
            const float4 c = *(const float4*)(wp + 4);
            uint4 o;
            o.x = f2bf(a.x) | ((unsigned)f2bf(a.y) << 16);
            o.y = f2bf(a.z) | ((unsigned)f2bf(a.w) << 16);
            o.z = f2bf(c.x) | ((unsigned)f2bf(c.y) << 16);
            o.w = f2bf(c.z) | ((unsigned)f2bf(c.w) << 16);
            *(uint4*)&Bs[row * 40 + off * 8] = o;
        }
        __syncthreads();
        short8 a[2], b[4];
#pragma unroll
        for (int rt = 0; rt < 2; rt++)
            a[rt] = *(const short8*)&As[(w * 32 + rt * 16 + l16) * 40 + quad * 8];
#pragma unroll
        for (int ct = 0; ct < 4; ct++)
            b[ct] = *(const short8*)&Bs[(ct * 16 + l16) * 40 + quad * 8];
#pragma unroll
        for (int rt = 0; rt < 2; rt++)
#pragma unroll
            for (int ct = 0; ct < 4; ct++)
                acc[rt][ct] = __builtin_amdgcn_mfma_f32_16x16x32_bf16(
                    a[rt], b[ct], acc[rt][ct], 0, 0, 0);
        __syncthreads();
    }

    // Epilogue: bias + bf16 into As (stride 72), then coalesced uint4 stores
#pragma unroll
    for (int rt = 0; rt < 2; rt++) {
#pragma unroll
        for (int ct = 0; ct < 4; ct++) {
            const int col = ct * 16 + l16;
            const float bb = bias[o0 + col];
#pragma unroll
            for (int reg = 0; reg < 4; reg++) {
                const int row = w * 32 + rt * 16 + quad * 4 + reg;
                As[row * 72 + col] = f2bf(acc[rt][ct][reg] + bb);
            }
        }
    }
    __syncthreads();
#pragma unroll
    for (int u = 0; u < 4; u++) {
        const int cid = t + u * 256;            // 0..1023
        const int row = cid >> 3;               // 0..127
        const int off = (cid & 7) * 8;          // 0..56 (ushorts)
        *(uint4*)&out[(size_t)(m0 + row) * 256 + o0 + off] =
            *(const uint4*)&As[row * 72 + off];
    }
}

// ---------------------------------------------------------------------------
// Top-40 + gather via RADIX-SELECT (R6-verified). grid (B), block 1024.
// kmat bf16; sel written fp32.
// ---------------------------------------------------------------------------
__global__ __launch_bounds__(1024) void topk_gather(const float* __restrict__ score,
                                                    const ushort_t* __restrict__ kmat,
                                                    float* __restrict__ sel) {
    const int b = blockIdx.x;
    const int t = threadIdx.x;
    __shared__ unsigned hist[256];
    __shared__ unsigned wsum[64];
    __shared__ unsigned sPrefix, sMask, sRem, sNeq;
    __shared__ int sNgt;
    __shared__ int top[NLM];
    __shared__ unsigned topkey[NLM];

    unsigned key[8];
#pragma unroll
    for (int j = 0; j < 8; j++) {
        const unsigned u = __float_as_uint(score[(size_t)b * SEQ + t + j * 1024]);
        key[j] = u ^ (unsigned)(((int)u >> 31) | 0x80000000);
    }
    if (t == 0) { sPrefix = 0; sMask = 0; sRem = NLM; sNgt = 0; sNeq = 0; }

    for (int lvl = 0; lvl < 4; lvl++) {
        const int shift = 24 - 8 * lvl;
        if (t < 256) hist[t] = 0;
        __syncthreads();
        const unsigned pfx = sPrefix, msk = sMask;
#pragma unroll
        for (int j = 0; j < 8; j++)
            if (((key[j] ^ pfx) & msk) == 0)
                atomicAdd(&hist[(key[j] >> shift) & 255u], 1u);
        __syncthreads();
        if (t < 64) wsum[t] = hist[t * 4] + hist[t * 4 + 1] + hist[t * 4 + 2] + hist[t * 4 + 3];
        __syncthreads();
        if (t == 0) {
            unsigned rem = sRem, cum = 0;
            int g = 63;
            for (; g > 0; g--) { if (cum + wsum[g] >= rem) break; cum += wsum[g]; }
            int d = g * 4 + 3;
            for (; d > g * 4; d--) { if (cum + hist[d] >= rem) break; cum += hist[d]; }
            sRem = rem - cum;
            sPrefix |= ((unsigned)d) << shift;
            sMask |= 255u << shift;
        }
        __syncthreads();
    }
    const unsigned K40 = sPrefix;
    const unsigned rem = sRem;
    const int ngt = NLM - (int)rem;

#pragma unroll
    for (int j = 0; j < 8; j++) {
        if (key[j] > K40) {
            const int slot = atomicAdd(&sNgt, 1);
            top[slot] = t + j * 1024; topkey[slot] = key[j];
        } else if (key[j] == K40) {
            const unsigned e = atomicAdd(&sNeq, 1u);
            if (e < rem) {
                const int slot = ngt + (int)e;
                top[slot] = t + j * 1024; topkey[slot] = key[j];
            }
        }
    }
    __syncthreads();

    if (t < 64) {
        unsigned long long c = (t < NLM)
            ? ((((unsigned long long)(~topkey[t])) << 32) | (unsigned)top[t])
            : 0xFFFFFFFFFFFFFFFFull;
#pragma unroll
        for (int kk = 2; kk <= 64; kk <<= 1) {
#pragma unroll
            for (int j = kk >> 1; j >= 1; j >>= 1) {
                const unsigned long long o = __shfl_xor(c, j);
                const bool takeMin = ((t & kk) == 0) == ((t & j) == 0);
                const bool less = c < o;
                c = (takeMin == less) ? c : o;
            }
        }
        if (t < NLM) top[t] = (int)(c & 0xFFFFFFFFu);
    }
    __syncthreads();

    for (int f = t; f < NLM * 256; f += 1024) {
        const int j = f >> 8;
        const int cc = f & 255;
        sel[(size_t)b * SEQ * 0 + (size_t)b * NLM * 256 + f] = bf2f(kmat[((size_t)b * SEQ + top[j]) * 256 + cc]);
    }
}

// ---------------------------------------------------------------------------
// sim_fused: grid (SEQ/64, B, 2), block 256.
//   Both z: logits+softmax for 64 rows vs 40 landmarks (A = qbf or kbf).
//   z=0: write simq to global (consumed by out_pre).
//   z=1: simk NEVER hits global — softmaxed values go to LDS (Ps), then the
//        tmat accumulation (R10's tmat_kernel body) runs in-place: stage v
//        tile (bf16) over the dead logits buffers, thread t owns column t,
//        tac[40], 40 atomics into pre-zeroed tmat. Saves one dispatch and
//        5.2 MB of simk write+read traffic.
// LDS union: phase A (As_ 17.4K + St_ 10.9K = 28.3K) / phase B (Ps 10K +
// Vs 32K = 42K) -> 42 KB static, 3 blocks/CU.
// Bounded unroll on logits i-loop (R3 spill lesson).
// ---------------------------------------------------------------------------
__global__ __launch_bounds__(256, 4) void sim_fused(const ushort_t* __restrict__ qbf,
                                                    const ushort_t* __restrict__ kbf,
                                                    const ushort_t* __restrict__ vbf,
                                                    const float* __restrict__ sel,
                                                    float* __restrict__ simq,
                                                    float* __restrict__ tmat) {
    __shared__ __align__(16) char smem[43008];
    float (*As_)[68] = (float(*)[68])smem;              // phase A: 17408 B
    float (*St_)[68] = (float(*)[68])(smem + 17408);    // phase A: 10880 B
    float (*Ps)[40]  = (float(*)[40])smem;              // phase B: 10240 B
    ushort_t* Vs     = (ushort_t*)(smem + 10240);       // phase B: 32768 B
    const int b = blockIdx.y;
    const int n0 = blockIdx.x * 64;
    const int t = threadIdx.x;
    const int r = t >> 2, c = t & 3;
    const ushort_t* __restrict__ A = (blockIdx.z == 0) ? qbf : kbf;
    const ushort_t* __restrict__ Arow = A + ((size_t)b * SEQ + n0) * 256;
    const float* __restrict__ Sb = sel + (size_t)b * NLM * 256;

    float acc[10];
#pragma unroll
    for (int j = 0; j < 10; j++) acc[j] = 0.f;

    for (int kc = 0; kc < 256; kc += 64) {
#pragma unroll
        for (int u = 0; u < 4; u++) {
            const int f = t + u * 256;
            const int row = f >> 4;
            const int c4 = (f & 15) * 4;
            const uint2 raw = *(const uint2*)&Arow[(size_t)row * 256 + kc + c4];
            float4 fa;
            fa.x = __uint_as_float((raw.x & 0xFFFFu) << 16);
            fa.y = __uint_as_float(raw.x & 0xFFFF0000u);
            fa.z = __uint_as_float((raw.y & 0xFFFFu) << 16);
            fa.w = __uint_as_float(raw.y & 0xFFFF0000u);
            *(float4*)&As_[row][c4] = fa;
        }
#pragma unroll
        for (int u = 0; u < 3; u++) {
            const int f = t + u * 256;
            if (f < 640) {
                const int row = f >> 4;
                const int c4 = (f & 15) * 4;
                *(float4*)&St_[row][c4] = *(const float4*)&Sb[(size_t)row * 256 + kc + c4];
            }
        }
        __syncthreads();
#pragma unroll 1
        for (int i = 0; i < 64; i += 4) {
            const float4 a = *(const float4*)&As_[r][i];
#pragma unroll
            for (int j = 0; j < 10; j++) {
                const float4 s = *(const float4*)&St_[c * 10 + j][i];
                acc[j] = fmaf(a.x, s.x, acc[j]);
                acc[j] = fmaf(a.y, s.y, acc[j]);
                acc[j] = fmaf(a.z, s.z, acc[j]);
                acc[j] = fmaf(a.w, s.w, acc[j]);
            }
        }
        __syncthreads();
    }

    float mx = -1e30f;
#pragma unroll
    for (int j = 0; j < 10; j++) {
        acc[j] *= INV_SCALE;
        mx = fmaxf(mx, acc[j]);
    }
    mx = fmaxf(mx, __shfl_xor(mx, 1));
    mx = fmaxf(mx, __shfl_xor(mx, 2));
    float sum = 0.f;
#pragma unroll
    for (int j = 0; j < 10; j++) {
        acc[j] = expf(acc[j] - mx);
        sum += acc[j];
    }
    sum += __shfl_xor(sum, 1);
    sum += __shfl_xor(sum, 2);
    const float inv = 1.f / sum;
#pragma unroll
    for (int j = 0; j < 10; j++) acc[j] *= inv;

    if (blockIdx.z == 0) {
        float* __restrict__ dst = &simq[((size_t)b * SEQ + n0 + r) * NLM + c * 10];
#pragma unroll
        for (int j2 = 0; j2 < 5; j2++) {
            float2 o; o.x = acc[2 * j2]; o.y = acc[2 * j2 + 1];
            *(float2*)&dst[2 * j2] = o;
        }
        return;
    }

    // ---- z=1: tmat accumulation in-place (simk stays on-chip) ----
    // All LDS reads of As_/St_ are done (trailing barrier of the kc loop);
    // safe to overwrite with Ps/Vs.
#pragma unroll
    for (int j = 0; j < 10; j++) Ps[r][c * 10 + j] = acc[j];
#pragma unroll
    for (int u = 0; u < 8; u++) {
        const int cid = t + u * 256;          // 0..2047
        const int row = cid >> 5, off = (cid & 31) * 8;
        *(uint4*)&Vs[row * 256 + off] =
            *(const uint4*)&vbf[((size_t)b * SEQ + n0 + row) * 256 + off];
    }
    __syncthreads();

    float tac[40];
#pragma unroll
    for (int j = 0; j < 40; j++) tac[j] = 0.f;

#pragma unroll 2
    for (int m = 0; m < 64; m++) {
        const float vv = bf2f(Vs[m * 256 + t]);   // 2-way bank alias: free
#pragma unroll
        for (int j4 = 0; j4 < 10; j4++) {
            const float4 p = *(const float4*)&Ps[m][j4 * 4];  // broadcast
            tac[j4 * 4 + 0] = fmaf(p.x, vv, tac[j4 * 4 + 0]);
            tac[j4 * 4 + 1] = fmaf(p.y, vv, tac[j4 * 4 + 1]);
            tac[j4 * 4 + 2] = fmaf(p.z, vv, tac[j4 * 4 + 2]);
            tac[j4 * 4 + 3] = fmaf(p.w, vv, tac[j4 * 4 + 3]);
        }
    }
#pragma unroll
    for (int j = 0; j < 40; j++)
        atomicAdd(&tmat[(size_t)b * NLM * 256 + j * 256 + t], tac[j]);
}

// ---------------------------------------------------------------------------
// out_pre[g][cc] = sum_l simq[g][l] * t[b][l][cc] -> bf16 (feeds final GEMM).
// grid (MROWS/64), block 256.
// ---------------------------------------------------------------------------
__global__ __launch_bounds__(256) void out_pre_kernel(const float* __restrict__ simq,
                                                      const float* __restrict__ tmat,
                                                      ushort_t* __restrict__ outp_bf) {
    __shared__ float Pm[64][40];
    const int g0 = blockIdx.x * 64;
    const int b = g0 >> 13;
    const int t = threadIdx.x;
    float* pflat = &Pm[0][0];
    for (int f = t; f < 64 * NLM; f += 256) pflat[f] = simq[(size_t)g0 * NLM + f];
    float tc[40];
#pragma unroll
    for (int l = 0; l < 40; l++) tc[l] = tmat[(size_t)b * NLM * 256 + l * 256 + t];
    __syncthreads();
#pragma unroll 2
    for (int m = 0; m < 64; m++) {
        float a = 0.f;
#pragma unroll
        for (int j4 = 0; j4 < 10; j4++) {
            const float4 p = *(const float4*)&Pm[m][j4 * 4];
            a = fmaf(p.x, tc[j4 * 4 + 0], a);
            a = fmaf(p.y, tc[j4 * 4 + 1], a);
            a = fmaf(p.z, tc[j4 * 4 + 2], a);
            a = fmaf(p.w, tc[j4 * 4 + 3], a);
        }
        outp_bf[((size_t)g0 + m) * 256 + t] = f2bf(a);
    }
}

// ---------------------------------------------------------------------------
// gemm_out: final projection. A bf16, Wo fp32 (converted during staging),
// fp32 out with bias + residual via LDS-transpose epilogue. grid (4, 128).
// ---------------------------------------------------------------------------
__global__ __launch_bounds__(256) void gemm_out(const ushort_t* __restrict__ Abf,
                                                const float* __restrict__ Wo,
                                                const float* __restrict__ bias,
                                                const float* __restrict__ resid,
                                                float* __restrict__ out) {
    __shared__ __align__(16) char smem[128 * 68 * 4];   // 34.8 KB
    ushort_t* As = (ushort_t*)smem;                      // 10 KB  (128*40)
    ushort_t* Bs = (ushort_t*)(smem + 128 * 40 * 2);     // 5 KB   (64*40)
    float* Ft = (float*)smem;                            // 128*68 floats
    const int t = threadIdx.x;
    const int o0 = blockIdx.x * 64;
    const int m0 = blockIdx.y * 128;
    const int lane = t & 63;
    const int w = t >> 6;
    const int quad = lane >> 4;
    const int l16 = lane & 15;

    floatx4 acc[2][4];
#pragma unroll
    for (int rt = 0; rt < 2; rt++)
#pragma unroll
        for (int ct = 0; ct < 4; ct++) acc[rt][ct] = (floatx4){0.f, 0.f, 0.f, 0.f};

    for (int kc = 0; kc < 256; kc += 32) {
#pragma unroll
        for (int u = 0; u < 2; u++) {
            const int cid = t + u * 256;
            const int row = cid >> 2, off = cid & 3;
            *(uint4*)&As[row * 40 + off * 8] =
                *(const uint4*)&Abf[(size_t)(m0 + row) * 256 + kc + off * 8];
        }
        {
            const int row = t >> 2, off = t & 3;
            const float* wp = &Wo[(size_t)(o0 + row) * 256 + kc + off * 8];
            const float4 a = *(const float4*)wp;
            const float4 c = *(const float4*)(wp + 4);
            uint4 o;
            o.x = f2bf(a.x) | ((unsigned)f2bf(a.y) << 16);
            o.y = f2bf(a.z) | ((unsigned)f2bf(a.w) << 16);
            o.z = f2bf(c.x) | ((unsigned)f2bf(c.y) << 16);
            o.w = f2bf(c.z) | ((unsigned)f2bf(c.w) << 16);
            *(uint4*)&Bs[row * 40 + off * 8] = o;
        }
        __syncthreads();
        short8 a[2], b[4];
#pragma unroll
        for (int rt = 0; rt < 2; rt++)
            a[rt] = *(const short8*)&As[(w * 32 + rt * 16 + l16) * 40 + quad * 8];
#pragma unroll
        for (int ct = 0; ct < 4; ct++)
            b[ct] = *(const short8*)&Bs[(ct * 16 + l16) * 40 + quad * 8];
#pragma unroll
        for (int rt = 0; rt < 2; rt++)
#pragma unroll
            for (int ct = 0; ct < 4; ct++)
                acc[rt][ct] = __builtin_amdgcn_mfma_f32_16x16x32_bf16(
                    a[rt], b[ct], acc[rt][ct], 0, 0, 0);
        __syncthreads();
    }

#pragma unroll
    for (int rt = 0; rt < 2; rt++) {
#pragma unroll
        for (int ct = 0; ct < 4; ct++) {
            const int col = ct * 16 + l16;
            const float bb = bias[o0 + col];
#pragma unroll
            for (int reg = 0; reg < 4; reg++) {
                const int row = w * 32 + rt * 16 + quad * 4 + reg;
                Ft[row * 68 + col] = acc[rt][ct][reg] + bb;
            }
        }
    }
    __syncthreads();
#pragma unroll
    for (int u = 0; u < 8; u++) {
        const int cid = t + u * 256;            // 0..2047
        const int row = cid >> 4;               // 0..127
        const int off = (cid & 15) * 4;         // 0..60 (floats)
        const float4 v = *(const float4*)&Ft[row * 68 + off];
        const float4 r4 = *(const float4*)&resid[(size_t)(m0 + row) * 256 + o0 + off];
        float4 o;
        o.x = v.x + r4.x; o.y = v.y + r4.y; o.z = v.z + r4.z; o.w = v.w + r4.w;
        *(float4*)&out[(size_t)(m0 + row) * 256 + o0 + off] = o;
    }
}

// ---------------------------------------------------------------------------
// Workspace (~37 MB). 7 dispatches (was 9): score folded into gemm_qkv as a
// z-slice; tmat accumulation folded into sim (simk never materialized).
// outp_bf ALIASES xbf (dead after gemm_qkv_score).
// ---------------------------------------------------------------------------
extern "C" void kernel_launch(void* const* d_in, const int* in_sizes, int n_in,
                              void* d_out, int out_size, void* d_ws, size_t ws_size,
                              hipStream_t stream) {
    const float* query = (const float*)d_in[0];
    const float* Wq = (const float*)d_in[1];
    const float* bq = (const float*)d_in[2];
    const float* Wk = (const float*)d_in[3];
    const float* bk = (const float*)d_in[4];
    const float* Wv = (const float*)d_in[5];
    const float* bv = (const float*)d_in[6];
    const float* Wo = (const float*)d_in[7];
    const float* bo = (const float*)d_in[8];
    float* out = (float*)d_out;

    char* p = (char*)d_ws;
    float* simq  = (float*)p;            p += (size_t)MROWS * NLM * 4;      // 2.62 MB
    float* sel   = (float*)p;            p += (size_t)BATCH * NLM * 256 * 4;
    float* tmat  = (float*)p;            p += (size_t)BATCH * NLM * 256 * 4;
    float* partial = (float*)p;          p += (size_t)BATCH * NCBLK * 256 * 4; // 512 KB
    float* ws    = (float*)p;            p += (size_t)BATCH * 256 * 4;
    float* score = (float*)p;            p += (size_t)BATCH * SEQ * 4;
    ushort_t* qkv = (ushort_t*)p;        p += (size_t)3 * MROWS * 256 * 2;  // 25.2 MB
    ushort_t* xbf = (ushort_t*)p;        p += (size_t)MROWS * 256 * 2;      // 8.39 MB
    ushort_t* qbf = qkv;
    ushort_t* kbf = qkv + (size_t)MROWS * 256;
    ushort_t* vbf = qkv + (size_t)2 * MROWS * 256;
    ushort_t* outp_bf = xbf;  // alias: xbf dead after gemm_qkv_score

    const dim3 blk(256);

    convert_colsum<<<dim3(SEQ / 32, BATCH), blk, 0, stream>>>(query, xbf, partial);
    ws_kernel<<<dim3(BATCH), dim3(1024), 0, stream>>>(partial, Wq, bq, Wk, ws, tmat);

    gemm_qkv_score<<<dim3(4, MROWS / 128, 4), blk, 0, stream>>>(
        xbf, Wq, Wk, Wv, bq, bk, bv, qkv, query, ws, score);

    topk_gather<<<dim3(BATCH), dim3(1024), 0, stream>>>(score, kbf, sel);

    sim_fused<<<dim3(SEQ / 64, BATCH, 2), blk, 0, stream>>>(qbf, kbf, vbf, sel, simq, tmat);

    out_pre_kernel<<<dim3(MROWS / 64), blk, 0, stream>>>(simq, tmat, outp_bf);
    gemm_out<<<dim3(4, MROWS / 128), blk, 0, stream>>>(outp_bf, Wo, bo, query, out);
}